// Round 4
// baseline (906.142 us; speedup 1.0000x reference)
//
#include <hip/hip_runtime.h>
#include <stdint.h>

#define N_NODES 100000
#define N_EDGES 800000

typedef unsigned short u16;
typedef __attribute__((ext_vector_type(8))) short bf16x8;
typedef __attribute__((ext_vector_type(8))) unsigned short ushort8;
typedef __attribute__((ext_vector_type(4))) float f32x4;
typedef __attribute__((ext_vector_type(4))) int i32x4;
typedef __attribute__((ext_vector_type(4))) unsigned int u32x4;

struct alignas(8) U16x4 { u16 x, y, z, w; };

__device__ __forceinline__ u16 f2b(float f) {
    union { float f; unsigned u; } x; x.f = f;
    unsigned r = (x.u + 0x7FFFu + ((x.u >> 16) & 1u)) >> 16;
    return (u16)r;
}
__device__ __forceinline__ float b2f(u16 h) {
    union { unsigned u; float f; } x; x.u = ((unsigned)h) << 16;
    return x.f;
}
// monotone bf16 -> u16 key: float order == unsigned order
__device__ __forceinline__ u16 keyb(u16 h) {
    u16 m = (u16)((short)h >> 15);                 // 0xFFFF if negative
    return (u16)(h ^ (0x8000u | (m & 0x7FFFu)));
}
__device__ __forceinline__ u16 unkey(u16 k) {
    u16 m = (u16)((short)k >> 15);                 // 0xFFFF if orig positive
    return (u16)(k ^ (0x8000u | (~m & 0x7FFFu)));
}
__device__ __forceinline__ unsigned pkmax(unsigned a, unsigned b) {
    unsigned d;
    asm("v_pk_max_u16 %0, %1, %2" : "=v"(d) : "v"(a), "v"(b));
    return d;
}
__device__ __forceinline__ u32x4 pkmax4(u32x4 a, u32x4 b) {
    u32x4 r;
    r.x = pkmax(a.x, b.x); r.y = pkmax(a.y, b.y);
    r.z = pkmax(a.z, b.z); r.w = pkmax(a.w, b.w);
    return r;
}

__device__ __forceinline__ void gload_lds16(const void* g, void* l) {
    __builtin_amdgcn_global_load_lds(
        (const __attribute__((address_space(1))) char*)(uintptr_t)g,
        (__attribute__((address_space(3))) char*)(uintptr_t)l,
        16, 0, 0);
}

// ---------------- fused input cast + keyed conf + deg zeroing ----------------

__global__ void k_prep(const float* __restrict__ conf, const float* __restrict__ node,
                       u16* __restrict__ conf16, u16* __restrict__ node16,
                       u16* __restrict__ keyed, int* __restrict__ deg) {
    const int c4 = N_NODES * 64 / 4;
    const int n4 = N_NODES * 192 / 4;
    int i = blockIdx.x * blockDim.x + threadIdx.x;
    if (i < c4) {
        float4 v = ((const float4*)conf)[i];
        U16x4 o; o.x = f2b(v.x); o.y = f2b(v.y); o.z = f2b(v.z); o.w = f2b(v.w);
        ((U16x4*)conf16)[i] = o;
        U16x4 ko; ko.x = keyb(o.x); ko.y = keyb(o.y); ko.z = keyb(o.z); ko.w = keyb(o.w);
        int n = i >> 4;                       // 16 float4 per 64-dim row
        ((U16x4*)keyed)[n * 64 + (i & 15)] = ko;
    } else if (i < c4 + n4) {
        float4 v = ((const float4*)node)[i - c4];
        U16x4 o; o.x = f2b(v.x); o.y = f2b(v.y); o.z = f2b(v.z); o.w = f2b(v.w);
        ((U16x4*)node16)[i - c4] = o;
    } else if (i < c4 + n4 + N_NODES / 4) {
        i32x4 z = {0, 0, 0, 0};
        ((i32x4*)deg)[i - c4 - n4] = z;
    }
}

// ---------------- fused weight packing (fragment order) ----------------

struct PackSeg { const float* a; const float* b; u16* dst; int K0, K1, Ncol, beg, end; };
struct PackArgs { PackSeg s[8]; };

__global__ void k_pack(PackArgs p, int total) {
    int idx = blockIdx.x * blockDim.x + threadIdx.x;
    if (idx >= total) return;
    #pragma unroll
    for (int si = 0; si < 8; ++si) {
        if (idx >= p.s[si].beg && idx < p.s[si].end) {
            int li = idx - p.s[si].beg;
            int Ncol = p.s[si].Ncol, K0 = p.s[si].K0;
            int kq = li & 7;
            int t = li >> 3;
            int c15 = t & 15; t >>= 4;
            int k8 = t & 3;  t >>= 2;
            int nb = Ncol >> 4;
            int cb = t % nb;
            int ks = t / nb;
            int col = cb * 16 + c15;
            int k = ks * 32 + k8 * 8 + kq;
            float v = (k < K0) ? p.s[si].a[(size_t)k * Ncol + col]
                               : p.s[si].b[(size_t)(k - K0) * Ncol + col];
            p.s[si].dst[li] = f2b(v);
        }
    }
}

// ---------------- CSR build ----------------

__global__ void k_count(const int* __restrict__ dst, int* __restrict__ deg) {
    int e = blockIdx.x * blockDim.x + threadIdx.x;
    if (e < N_EDGES) atomicAdd(&deg[dst[e]], 1);
}

__global__ void k_scan1(const int* __restrict__ deg, int* __restrict__ excl,
                        int* __restrict__ bsum, int n) {
    __shared__ int sh[512];
    int t = threadIdx.x;
    int base = blockIdx.x * 2048 + t * 4;
    int v0 = (base + 0 < n) ? deg[base + 0] : 0;
    int v1 = (base + 1 < n) ? deg[base + 1] : 0;
    int v2 = (base + 2 < n) ? deg[base + 2] : 0;
    int v3 = (base + 3 < n) ? deg[base + 3] : 0;
    int tot = v0 + v1 + v2 + v3;
    sh[t] = tot;
    __syncthreads();
    for (int off = 1; off < 512; off <<= 1) {
        int x = (t >= off) ? sh[t - off] : 0;
        __syncthreads();
        sh[t] += x;
        __syncthreads();
    }
    int run = sh[t] - tot;
    if (base + 0 < n) excl[base + 0] = run; run += v0;
    if (base + 1 < n) excl[base + 1] = run; run += v1;
    if (base + 2 < n) excl[base + 2] = run; run += v2;
    if (base + 3 < n) excl[base + 3] = run;
    if (t == 511) bsum[blockIdx.x] = sh[t];
}

__global__ void k_scan2(int* __restrict__ bsum, int nb) {
    __shared__ int sh[64];
    int t = threadIdx.x;
    int v = (t < nb) ? bsum[t] : 0;
    sh[t] = v;
    __syncthreads();
    for (int off = 1; off < 64; off <<= 1) {
        int x = (t >= off) ? sh[t - off] : 0;
        __syncthreads();
        sh[t] += x;
        __syncthreads();
    }
    if (t < nb) bsum[t] = sh[t] - v;
}

__global__ void k_scan3(int* __restrict__ excl, const int* __restrict__ bsum,
                        int* __restrict__ cursor, int n) {
    int i = blockIdx.x * blockDim.x + threadIdx.x;
    if (i < n) {
        int v = excl[i] + bsum[i >> 11];
        excl[i] = v;
        cursor[i] = v;
    }
}

__global__ void k_scatter(const int* __restrict__ src, const int* __restrict__ dst,
                          int* __restrict__ cursor, int* __restrict__ esrc) {
    int e = blockIdx.x * blockDim.x + threadIdx.x;
    if (e < N_EDGES) {
        int p = atomicAdd(&cursor[dst[e]], 1);
        esrc[p] = src[e];
    }
}

// ---------------- segment-max aggregation (keyed u16 domain) ----------------
// Gather source is the pre-keyed [N,256] mirror (keyed = monotone u16 map of
// bf16), so the max is v_pk_max_u16 -- no b2f/fmax in the hot loop.
// One wave per node, 4 nodes/block; block's CSR edge span staged in LDS.
// CHUNKS=32: full row (conf+x), 2 edges across wave halves; saves plain
//            conf-part max to aggC.
// CHUNKS=24: x-part only (cols 64..255), lanes 0-23/24-47 = 2 edges; lanes
//            48-55 copy aggC into output.
// All rounds 8-edge full unrolls with indices clamped to d-1 (dup-safe).

template<int CHUNKS>
__global__ __launch_bounds__(256) void k_agg(
    const u16* __restrict__ keyed,
    const int* __restrict__ indptr, const int* __restrict__ deg,
    const int* __restrict__ iend, const int* __restrict__ esrc,
    u16* __restrict__ agg, u16* __restrict__ aggC) {
    __shared__ int se[512];
    __shared__ int sinfo[2];
    const int b4 = blockIdx.x * 4;
    if (threadIdx.x == 0) {
        sinfo[0] = indptr[b4];
        sinfo[1] = iend[b4 + 3];
    }
    __syncthreads();
    const int sbase = sinfo[0];
    const int slen = sinfo[1] - sbase;
    const bool useLds = slen <= 512;
    if (useLds) {
        for (int i = threadIdx.x; i < slen; i += 256) se[i] = esrc[sbase + i];
    }
    __syncthreads();

    const int node = b4 + (threadIdx.x >> 6);
    const int lane = threadIdx.x & 63;
    constexpr int ACTIVE = (CHUNKS == 32) ? 64 : 48;
    const int e_sub = (CHUNKS == 32) ? (lane >> 5) : (lane >= 24 ? 1 : 0);
    int ch = lane - e_sub * CHUNKS;
    if (ch < 0 || ch >= CHUNKS) ch = 0;   // inactive lanes: safe addr
    const int start = indptr[node];
    const int d = deg[node];
    const u16* bp = keyed + ((CHUNKS == 32) ? 0 : 64) + ch * 8;

    u32x4 m = {0u, 0u, 0u, 0u};           // key 0 == -NaN == identity for max

    if (lane < ACTIVE && d > 0) {
        const int rounds = (d + 7) >> 3;
        const int lbase = start - sbase;
        for (int rr = 0; rr < rounds; ++rr) {
            const int b0 = rr * 8 + e_sub;
            const int dm1 = d - 1;
            int i0 = min(b0, dm1), i1 = min(b0 + 2, dm1);
            int i2 = min(b0 + 4, dm1), i3 = min(b0 + 6, dm1);
            int s0, s1, s2, s3;
            if (useLds) {
                s0 = se[lbase + i0]; s1 = se[lbase + i1];
                s2 = se[lbase + i2]; s3 = se[lbase + i3];
            } else {
                s0 = esrc[start + i0]; s1 = esrc[start + i1];
                s2 = esrc[start + i2]; s3 = esrc[start + i3];
            }
            u32x4 v0 = *(const u32x4*)(bp + (size_t)s0 * 256);
            u32x4 v1 = *(const u32x4*)(bp + (size_t)s1 * 256);
            u32x4 v2 = *(const u32x4*)(bp + (size_t)s2 * 256);
            u32x4 v3 = *(const u32x4*)(bp + (size_t)s3 * 256);
            m = pkmax4(m, pkmax4(pkmax4(v0, v1), pkmax4(v2, v3)));
        }
    }

    // combine the two edge-subsets
    if (CHUNKS == 32) {
        m.x = pkmax(m.x, __shfl_xor(m.x, 32, 64));
        m.y = pkmax(m.y, __shfl_xor(m.y, 32, 64));
        m.z = pkmax(m.z, __shfl_xor(m.z, 32, 64));
        m.w = pkmax(m.w, __shfl_xor(m.w, 32, 64));
    } else {
        m.x = pkmax(m.x, __shfl(m.x, lane + 24, 64));
        m.y = pkmax(m.y, __shfl(m.y, lane + 24, 64));
        m.z = pkmax(m.z, __shfl(m.z, lane + 24, 64));
        m.w = pkmax(m.w, __shfl(m.w, lane + 24, 64));
    }

    // unkey -> plain bf16; d==0 -> 0.0
    unsigned wv[4] = {m.x, m.y, m.z, m.w};
    ushort8 o;
    #pragma unroll
    for (int j = 0; j < 4; ++j) {
        u16 klo = (u16)(wv[j] & 0xFFFFu), khi = (u16)(wv[j] >> 16);
        o[2 * j]     = (d > 0) ? unkey(klo) : (u16)0;
        o[2 * j + 1] = (d > 0) ? unkey(khi) : (u16)0;
    }

    if (CHUNKS == 32) {
        if (lane < 32) {
            *(ushort8*)(agg + (size_t)node * 256 + lane * 8) = o;
            if (lane < 8)
                *(ushort8*)(aggC + (size_t)node * 64 + lane * 8) = o;
        }
    } else {
        if (lane < 24) {
            *(ushort8*)(agg + (size_t)node * 256 + 64 + lane * 8) = o;
        } else if (lane >= 48 && lane < 56) {
            const int c2 = lane - 48;
            ushort8 v = *(const ushort8*)(aggC + (size_t)node * 64 + c2 * 8);
            *(ushort8*)(agg + (size_t)node * 256 + c2 * 8) = v;
        }
    }
}

// ---------------- MFMA GEMM ----------------
// C[nrows, BN] = concat_K(A0|A1|A2) @ Bt^T (+bias, +epilogue)
// Bt prepacked in fragment order; A staged via global_load_lds with permuted
// SOURCE index so LDS lands in fragment order -> conflict-free ds_read_b128.
// EPI: 0 = bias -> bf16                         (sage linear)
//      1 = bias,lrelu -> bf16                   (prenet hidden, mlp hidden)
//      3 = bf16resid + lrelu -> bf16            (mlp0 final)
//      4 = bf16resid + lrelu -> f32 d_out       (mlp1 final)
//      5 = 1 + keyed store                      (prenet final)
//      6 = 3 + keyed store                      (mlp0 final, keyed for L1)

template<int BN, int EPI>
__global__ __launch_bounds__(512, 6) void k_gemm(
    const u16* __restrict__ A0, int K0,
    const u16* __restrict__ A1, int K1,
    const u16* __restrict__ A2, int K2,
    const u16* __restrict__ Bt,
    const float* __restrict__ bias,
    float* __restrict__ outf,
    u16* __restrict__ outb,
    const u16* __restrict__ resid16,
    u16* __restrict__ keyed,
    int nrows)
{
    constexpr int FN = BN / 64;           // b-frags per wave (4 or 3)
    constexpr int ASZ = 128 * 32;         // A tile elems
    constexpr int BSLOTS = BN * 4;        // 16B slots in B tile
    __shared__ u16 lds[2][ASZ + BN * 32] __attribute__((aligned(16)));

    const int tid = threadIdx.x;
    const int wave = tid >> 6;
    const int lane = tid & 63;
    const int wr = wave >> 2;             // 0..1
    const int wc = wave & 3;              // 0..3
    const int rowbase = blockIdx.x * 128;
    const int Ktot = K0 + K1 + K2;
    const int nk = Ktot >> 5;

    f32x4 zero = {0.f, 0.f, 0.f, 0.f};
    f32x4 acc[4][FN];
    #pragma unroll
    for (int fm = 0; fm < 4; ++fm)
        #pragma unroll
        for (int fn = 0; fn < FN; ++fn)
            acc[fm][fn] = zero;

    auto stage = [&](int buf, int ks) {
        const int k0 = ks * 32;
        const u16* segp; int segoff, segK;
        if (k0 < K0)           { segp = A0; segoff = k0;           segK = K0; }
        else if (k0 < K0 + K1) { segp = A1; segoff = k0 - K0;      segK = K1; }
        else                   { segp = A2; segoff = k0 - K0 - K1; segK = K2; }
        {   // A tile in fragment order: slot tid -> row = wave*16 + (tid&15),
            // k8 = (tid>>4)&3 ; LDS dest linear (wave-uniform base + lane*16)
            int row = ((tid >> 6) << 4) | (tid & 15);
            int grow = rowbase + row;
            if (grow >= nrows) grow = nrows - 1;
            const u16* g = segp + (size_t)grow * segK + segoff + ((tid >> 4) & 3) * 8;
            gload_lds16(g, &lds[buf][wave * 512]);
        }
        #pragma unroll
        for (int it = 0; it < (BSLOTS + 511) / 512; ++it) {
            int slot = it * 512 + tid;
            if (slot < BSLOTS) {          // wave-uniform predicate
                const u16* g = Bt + (size_t)ks * BN * 32 + slot * 8;
                gload_lds16(g, &lds[buf][ASZ + it * 4096 + wave * 512]);
            }
        }
    };

    stage(0, 0);
    __syncthreads();

    const int l15 = lane & 15, l4 = lane >> 4;

    for (int ks = 0; ks < nk; ++ks) {
        const int cur = ks & 1;
        if (ks + 1 < nk) stage(cur ^ 1, ks + 1);
        const u16* la = &lds[cur][0];
        const u16* lb = &lds[cur][ASZ];
        bf16x8 a[4], b[FN];
        #pragma unroll
        for (int fm = 0; fm < 4; ++fm)
            a[fm] = *(const bf16x8*)(la + (wr * 4 + fm) * 512 + lane * 8);
        #pragma unroll
        for (int fn = 0; fn < FN; ++fn)
            b[fn] = *(const bf16x8*)(lb + (wc * FN + fn) * 512 + lane * 8);
        #pragma unroll
        for (int fm = 0; fm < 4; ++fm)
            #pragma unroll
            for (int fn = 0; fn < FN; ++fn)
                acc[fm][fn] = __builtin_amdgcn_mfma_f32_16x16x32_bf16(a[fm], b[fn], acc[fm][fn], 0, 0, 0);
        __syncthreads();
    }

    // epilogue: C/D layout col = lane&15, row = (lane>>4)*4 + r
    const int r0 = rowbase + wr * 64;
    const int c0 = wc * (FN * 16);
    #pragma unroll
    for (int fn = 0; fn < FN; ++fn) {
        const int col = c0 + fn * 16 + l15;
        const float bs = bias[col];
        #pragma unroll
        for (int fm = 0; fm < 4; ++fm) {
            #pragma unroll
            for (int r = 0; r < 4; ++r) {
                const int row = r0 + fm * 16 + l4 * 4 + r;
                if (row < nrows) {
                    float v = acc[fm][fn][r] + bs;
                    if (EPI >= 1) v = (v >= 0.f) ? v : 0.2f * v;
                    if (EPI == 3 || EPI == 4 || EPI == 6) v += b2f(resid16[(size_t)row * BN + col]);
                    u16 hb = f2b(v);
                    if (EPI == 4) outf[(size_t)row * BN + col] = v;
                    else          outb[(size_t)row * BN + col] = hb;
                    if (EPI == 5 || EPI == 6)
                        keyed[(size_t)row * 256 + 64 + col] = keyb(hb);
                }
            }
        }
    }
}

// ---------------- host ----------------

extern "C" void kernel_launch(void* const* d_in, const int* in_sizes, int n_in,
                              void* d_out, int out_size, void* d_ws, size_t ws_size,
                              hipStream_t stream)
{
    (void)in_sizes; (void)n_in; (void)out_size; (void)ws_size;
    const float* node = (const float*)d_in[0];
    const float* conf = (const float*)d_in[1];
    const int* edges  = (const int*)d_in[2];
    const float* pw0  = (const float*)d_in[3];
    const float* pb0  = (const float*)d_in[4];
    const float* pw1  = (const float*)d_in[5];
    const float* pb1  = (const float*)d_in[6];
    const float* W[14];
    for (int i = 0; i < 14; ++i) W[i] = (const float*)d_in[7 + i];
    float* out = (float*)d_out;
    const int* e_src = edges;
    const int* e_dst = edges + N_EDGES;

    // keyed gather mirror [N,256] u16 (51.2MB) aliased onto d_out (76.8MB):
    // last keyed read (k_agg layer 1) precedes the only f32 writer (final GEMM),
    // and every keyed byte read is rewritten each launch (k_prep + epilogues).
    u16* keyed = (u16*)d_out;

    char* w = (char*)d_ws;
    auto alloc = [&](size_t b) { char* p = w; w += (b + 255) & ~(size_t)255; return p; };
    u16* conf16 = (u16*)alloc((size_t)N_NODES * 64 * 2);
    u16* node16 = (u16*)alloc((size_t)N_NODES * 192 * 2);   // prenet input, later h
    u16* x16    = (u16*)alloc((size_t)N_NODES * 192 * 2);   // bf16 residual stream
    u16* agg16  = (u16*)alloc((size_t)N_NODES * 256 * 2);   // agg, then s (in-place)
    u16* aggC   = (u16*)alloc((size_t)N_NODES * 64 * 2);    // saved conf-part max
    int* deg    = (int*)alloc((size_t)N_NODES * 4);
    int* indptr = (int*)alloc((size_t)N_NODES * 4);
    int* cursor = (int*)alloc((size_t)N_NODES * 4);         // becomes end-ptrs
    int* esrc   = (int*)alloc((size_t)N_EDGES * 4);
    int* bsum   = (int*)alloc(4096);
    u16* pw0t   = (u16*)alloc((size_t)192 * 256 * 2);
    u16* pw1t   = (u16*)alloc((size_t)192 * 192 * 2);
    u16 *sB[2], *mw0t[2], *mw1t[2];
    for (int l = 0; l < 2; ++l) {
        sB[l]   = (u16*)alloc((size_t)256 * 512 * 2);
        mw0t[l] = (u16*)alloc((size_t)192 * 256 * 2);
        mw1t[l] = (u16*)alloc((size_t)192 * 192 * 2);
    }

    // fused cast + keyed conf + deg zero
    {
        const int tot = N_NODES * 64 / 4 + N_NODES * 192 / 4 + N_NODES / 4;
        k_prep<<<(tot + 255) / 256, 256, 0, stream>>>(conf, node, conf16, node16, keyed, deg);
    }
    // fused weight packs (fragment order)
    {
        PackArgs pa;
        int off = 0;
        auto seg = [&](int i, const float* a, int K0, const float* b, int K1, int Ncol, u16* dst) {
            int sz = Ncol * (K0 + K1);
            pa.s[i] = {a, b, dst, K0, K1, Ncol, off, off + sz};
            off += sz;
        };
        seg(0, pw0, 256, nullptr, 0, 192, pw0t);
        seg(1, pw1, 192, nullptr, 0, 192, pw1t);
        seg(2, W[0], 256, W[2], 256, 256, sB[0]);
        seg(3, W[3], 256, nullptr, 0, 192, mw0t[0]);
        seg(4, W[5], 192, nullptr, 0, 192, mw1t[0]);
        seg(5, W[7], 256, W[9], 256, 256, sB[1]);
        seg(6, W[10], 256, nullptr, 0, 192, mw0t[1]);
        seg(7, W[12], 192, nullptr, 0, 192, mw1t[1]);
        k_pack<<<(off + 255) / 256, 256, 0, stream>>>(pa, off);
    }
    // CSR
    k_count<<<(N_EDGES + 255) / 256, 256, 0, stream>>>(e_dst, deg);
    int nb = (N_NODES + 2047) / 2048;
    k_scan1<<<nb, 512, 0, stream>>>(deg, indptr, bsum, N_NODES);
    k_scan2<<<1, 64, 0, stream>>>(bsum, nb);
    k_scan3<<<(N_NODES + 255) / 256, 256, 0, stream>>>(indptr, bsum, cursor, N_NODES);
    k_scatter<<<(N_EDGES + 255) / 256, 256, 0, stream>>>(e_src, e_dst, cursor, esrc);
    // cursor now holds per-node END pointers (indptr + deg)

    const int gblk = (N_NODES + 127) / 128;   // 782
    // prenet: x16 = lrelu(lrelu([conf|node]@w0+b0)@w1 + b1); final also fills keyed x
    k_gemm<192, 1><<<gblk, 512, 0, stream>>>(conf16, 64, node16, 192, nullptr, 0,
                                             pw0t, pb0, nullptr, x16, nullptr, nullptr, N_NODES);
    k_gemm<192, 5><<<gblk, 512, 0, stream>>>(x16, 192, nullptr, 0, nullptr, 0,
                                             pw1t, pb1, nullptr, x16, nullptr, keyed, N_NODES);
    for (int l = 0; l < 2; ++l) {
        if (l == 0)
            k_agg<32><<<N_NODES / 4, 256, 0, stream>>>(keyed, indptr, deg, cursor, esrc, agg16, aggC);
        else
            k_agg<24><<<N_NODES / 4, 256, 0, stream>>>(keyed, indptr, deg, cursor, esrc, agg16, aggC);
        // s = agg@wl + bl + [conf|x]@wr   (K=512 fused; in-place over agg16)
        k_gemm<256, 0><<<gblk, 512, 0, stream>>>(agg16, 256, conf16, 64, x16, 192,
                                                 sB[l], W[7*l+1], nullptr, agg16, nullptr, nullptr, N_NODES);
        // h = lrelu(s@mw0 + mb0)
        k_gemm<192, 1><<<gblk, 512, 0, stream>>>(agg16, 256, nullptr, 0, nullptr, 0,
                                                 mw0t[l], W[7*l+4], nullptr, node16, nullptr, nullptr, N_NODES);
        // x = x + lrelu(h@mw1 + mb1)
        if (l == 0)
            k_gemm<192, 6><<<gblk, 512, 0, stream>>>(node16, 192, nullptr, 0, nullptr, 0,
                                                     mw1t[l], W[7*l+6], nullptr, x16, x16, keyed, N_NODES);
        else
            k_gemm<192, 4><<<gblk, 512, 0, stream>>>(node16, 192, nullptr, 0, nullptr, 0,
                                                     mw1t[l], W[7*l+6], out, nullptr, x16, nullptr, N_NODES);
    }
}

// Round 5
// 595.206 us; speedup vs baseline: 1.5224x; 1.5224x over previous
//
#include <hip/hip_runtime.h>
#include <stdint.h>

#define N_NODES 100000
#define N_EDGES 800000

typedef unsigned short u16;
typedef __attribute__((ext_vector_type(8))) short bf16x8;
typedef __attribute__((ext_vector_type(8))) unsigned short ushort8;
typedef __attribute__((ext_vector_type(4))) float f32x4;
typedef __attribute__((ext_vector_type(4))) int i32x4;
typedef __attribute__((ext_vector_type(4))) unsigned int u32x4;

struct alignas(8) U16x4 { u16 x, y, z, w; };

__device__ __forceinline__ u16 f2b(float f) {
    union { float f; unsigned u; } x; x.f = f;
    unsigned r = (x.u + 0x7FFFu + ((x.u >> 16) & 1u)) >> 16;
    return (u16)r;
}
__device__ __forceinline__ float b2f(u16 h) {
    union { unsigned u; float f; } x; x.u = ((unsigned)h) << 16;
    return x.f;
}
// monotone bf16 -> u16 key: float order == unsigned order
__device__ __forceinline__ u16 keyb(u16 h) {
    u16 m = (u16)((short)h >> 15);                 // 0xFFFF if negative
    return (u16)(h ^ (0x8000u | (m & 0x7FFFu)));
}
__device__ __forceinline__ u16 unkey(u16 k) {
    u16 m = (u16)((short)k >> 15);                 // 0xFFFF if orig positive
    return (u16)(k ^ (0x8000u | (~m & 0x7FFFu)));
}
__device__ __forceinline__ unsigned pkmax(unsigned a, unsigned b) {
    unsigned d;
    asm("v_pk_max_u16 %0, %1, %2" : "=v"(d) : "v"(a), "v"(b));
    return d;
}
__device__ __forceinline__ u32x4 pkmax4(u32x4 a, u32x4 b) {
    u32x4 r;
    r.x = pkmax(a.x, b.x); r.y = pkmax(a.y, b.y);
    r.z = pkmax(a.z, b.z); r.w = pkmax(a.w, b.w);
    return r;
}

__device__ __forceinline__ void gload_lds16(const void* g, void* l) {
    __builtin_amdgcn_global_load_lds(
        (const __attribute__((address_space(1))) char*)(uintptr_t)g,
        (__attribute__((address_space(3))) char*)(uintptr_t)l,
        16, 0, 0);
}

// ---------------- fused input cast + keyed conf + deg zeroing ----------------

__global__ void k_prep(const float* __restrict__ conf, const float* __restrict__ node,
                       u16* __restrict__ conf16, u16* __restrict__ node16,
                       u16* __restrict__ keyed, int* __restrict__ deg) {
    const int c4 = N_NODES * 64 / 4;
    const int n4 = N_NODES * 192 / 4;
    int i = blockIdx.x * blockDim.x + threadIdx.x;
    if (i < c4) {
        float4 v = ((const float4*)conf)[i];
        U16x4 o; o.x = f2b(v.x); o.y = f2b(v.y); o.z = f2b(v.z); o.w = f2b(v.w);
        ((U16x4*)conf16)[i] = o;
        U16x4 ko; ko.x = keyb(o.x); ko.y = keyb(o.y); ko.z = keyb(o.z); ko.w = keyb(o.w);
        int n = i >> 4;                       // 16 float4 per 64-dim row
        ((U16x4*)keyed)[n * 64 + (i & 15)] = ko;
    } else if (i < c4 + n4) {
        float4 v = ((const float4*)node)[i - c4];
        U16x4 o; o.x = f2b(v.x); o.y = f2b(v.y); o.z = f2b(v.z); o.w = f2b(v.w);
        ((U16x4*)node16)[i - c4] = o;
    } else if (i < c4 + n4 + N_NODES / 4) {
        i32x4 z = {0, 0, 0, 0};
        ((i32x4*)deg)[i - c4 - n4] = z;
    }
}

// ---------------- fused weight packing (fragment order) ----------------

struct PackSeg { const float* a; const float* b; u16* dst; int K0, K1, Ncol, beg, end; };
struct PackArgs { PackSeg s[8]; };

__global__ void k_pack(PackArgs p, int total) {
    int idx = blockIdx.x * blockDim.x + threadIdx.x;
    if (idx >= total) return;
    #pragma unroll
    for (int si = 0; si < 8; ++si) {
        if (idx >= p.s[si].beg && idx < p.s[si].end) {
            int li = idx - p.s[si].beg;
            int Ncol = p.s[si].Ncol, K0 = p.s[si].K0;
            int kq = li & 7;
            int t = li >> 3;
            int c15 = t & 15; t >>= 4;
            int k8 = t & 3;  t >>= 2;
            int nb = Ncol >> 4;
            int cb = t % nb;
            int ks = t / nb;
            int col = cb * 16 + c15;
            int k = ks * 32 + k8 * 8 + kq;
            float v = (k < K0) ? p.s[si].a[(size_t)k * Ncol + col]
                               : p.s[si].b[(size_t)(k - K0) * Ncol + col];
            p.s[si].dst[li] = f2b(v);
        }
    }
}

// ---------------- CSR build ----------------

__global__ void k_count(const int* __restrict__ dst, int* __restrict__ deg) {
    int e = blockIdx.x * blockDim.x + threadIdx.x;
    if (e < N_EDGES) atomicAdd(&deg[dst[e]], 1);
}

__global__ void k_scan1(const int* __restrict__ deg, int* __restrict__ excl,
                        int* __restrict__ bsum, int n) {
    __shared__ int sh[512];
    int t = threadIdx.x;
    int base = blockIdx.x * 2048 + t * 4;
    int v0 = (base + 0 < n) ? deg[base + 0] : 0;
    int v1 = (base + 1 < n) ? deg[base + 1] : 0;
    int v2 = (base + 2 < n) ? deg[base + 2] : 0;
    int v3 = (base + 3 < n) ? deg[base + 3] : 0;
    int tot = v0 + v1 + v2 + v3;
    sh[t] = tot;
    __syncthreads();
    for (int off = 1; off < 512; off <<= 1) {
        int x = (t >= off) ? sh[t - off] : 0;
        __syncthreads();
        sh[t] += x;
        __syncthreads();
    }
    int run = sh[t] - tot;
    if (base + 0 < n) excl[base + 0] = run; run += v0;
    if (base + 1 < n) excl[base + 1] = run; run += v1;
    if (base + 2 < n) excl[base + 2] = run; run += v2;
    if (base + 3 < n) excl[base + 3] = run;
    if (t == 511) bsum[blockIdx.x] = sh[t];
}

__global__ void k_scan2(int* __restrict__ bsum, int nb) {
    __shared__ int sh[64];
    int t = threadIdx.x;
    int v = (t < nb) ? bsum[t] : 0;
    sh[t] = v;
    __syncthreads();
    for (int off = 1; off < 64; off <<= 1) {
        int x = (t >= off) ? sh[t - off] : 0;
        __syncthreads();
        sh[t] += x;
        __syncthreads();
    }
    if (t < nb) bsum[t] = sh[t] - v;
}

__global__ void k_scan3(int* __restrict__ excl, const int* __restrict__ bsum,
                        int* __restrict__ cursor, int n) {
    int i = blockIdx.x * blockDim.x + threadIdx.x;
    if (i < n) {
        int v = excl[i] + bsum[i >> 11];
        excl[i] = v;
        cursor[i] = v;
    }
}

__global__ void k_scatter(const int* __restrict__ src, const int* __restrict__ dst,
                          int* __restrict__ cursor, int* __restrict__ esrc) {
    int e = blockIdx.x * blockDim.x + threadIdx.x;
    if (e < N_EDGES) {
        int p = atomicAdd(&cursor[dst[e]], 1);
        esrc[p] = src[e];
    }
}

// ---------------- segment-max aggregation (keyed u16 domain) ----------------
// Gather source is the pre-keyed [N,256] mirror (keyed = monotone u16 map of
// bf16), so the max is v_pk_max_u16 -- no b2f/fmax in the hot loop.
// One wave per node, 4 nodes/block; block's CSR edge span staged in LDS.
// CHUNKS=32: full row (conf+x), 2 edges across wave halves; saves plain
//            conf-part max to aggC.
// CHUNKS=24: x-part only (cols 64..255), lanes 0-23/24-47 = 2 edges; lanes
//            48-55 copy aggC into output.
// All rounds 8-edge full unrolls with indices clamped to d-1 (dup-safe).

template<int CHUNKS>
__global__ __launch_bounds__(256) void k_agg(
    const u16* __restrict__ keyed,
    const int* __restrict__ indptr, const int* __restrict__ deg,
    const int* __restrict__ iend, const int* __restrict__ esrc,
    u16* __restrict__ agg, u16* __restrict__ aggC) {
    __shared__ int se[512];
    __shared__ int sinfo[2];
    const int b4 = blockIdx.x * 4;
    if (threadIdx.x == 0) {
        sinfo[0] = indptr[b4];
        sinfo[1] = iend[b4 + 3];
    }
    __syncthreads();
    const int sbase = sinfo[0];
    const int slen = sinfo[1] - sbase;
    const bool useLds = slen <= 512;
    if (useLds) {
        for (int i = threadIdx.x; i < slen; i += 256) se[i] = esrc[sbase + i];
    }
    __syncthreads();

    const int node = b4 + (threadIdx.x >> 6);
    const int lane = threadIdx.x & 63;
    constexpr int ACTIVE = (CHUNKS == 32) ? 64 : 48;
    const int e_sub = (CHUNKS == 32) ? (lane >> 5) : (lane >= 24 ? 1 : 0);
    int ch = lane - e_sub * CHUNKS;
    if (ch < 0 || ch >= CHUNKS) ch = 0;   // inactive lanes: safe addr
    const int start = indptr[node];
    const int d = deg[node];
    const u16* bp = keyed + ((CHUNKS == 32) ? 0 : 64) + ch * 8;

    u32x4 m = {0u, 0u, 0u, 0u};           // key 0 == -NaN == identity for max

    if (lane < ACTIVE && d > 0) {
        const int rounds = (d + 7) >> 3;
        const int lbase = start - sbase;
        for (int rr = 0; rr < rounds; ++rr) {
            const int b0 = rr * 8 + e_sub;
            const int dm1 = d - 1;
            int i0 = min(b0, dm1), i1 = min(b0 + 2, dm1);
            int i2 = min(b0 + 4, dm1), i3 = min(b0 + 6, dm1);
            int s0, s1, s2, s3;
            if (useLds) {
                s0 = se[lbase + i0]; s1 = se[lbase + i1];
                s2 = se[lbase + i2]; s3 = se[lbase + i3];
            } else {
                s0 = esrc[start + i0]; s1 = esrc[start + i1];
                s2 = esrc[start + i2]; s3 = esrc[start + i3];
            }
            u32x4 v0 = *(const u32x4*)(bp + (size_t)s0 * 256);
            u32x4 v1 = *(const u32x4*)(bp + (size_t)s1 * 256);
            u32x4 v2 = *(const u32x4*)(bp + (size_t)s2 * 256);
            u32x4 v3 = *(const u32x4*)(bp + (size_t)s3 * 256);
            m = pkmax4(m, pkmax4(pkmax4(v0, v1), pkmax4(v2, v3)));
        }
    }

    // combine the two edge-subsets
    if (CHUNKS == 32) {
        m.x = pkmax(m.x, __shfl_xor(m.x, 32, 64));
        m.y = pkmax(m.y, __shfl_xor(m.y, 32, 64));
        m.z = pkmax(m.z, __shfl_xor(m.z, 32, 64));
        m.w = pkmax(m.w, __shfl_xor(m.w, 32, 64));
    } else {
        m.x = pkmax(m.x, __shfl(m.x, lane + 24, 64));
        m.y = pkmax(m.y, __shfl(m.y, lane + 24, 64));
        m.z = pkmax(m.z, __shfl(m.z, lane + 24, 64));
        m.w = pkmax(m.w, __shfl(m.w, lane + 24, 64));
    }

    // unkey -> plain bf16; d==0 -> 0.0
    unsigned wv[4] = {m.x, m.y, m.z, m.w};
    ushort8 o;
    #pragma unroll
    for (int j = 0; j < 4; ++j) {
        u16 klo = (u16)(wv[j] & 0xFFFFu), khi = (u16)(wv[j] >> 16);
        o[2 * j]     = (d > 0) ? unkey(klo) : (u16)0;
        o[2 * j + 1] = (d > 0) ? unkey(khi) : (u16)0;
    }

    if (CHUNKS == 32) {
        if (lane < 32) {
            *(ushort8*)(agg + (size_t)node * 256 + lane * 8) = o;
            if (lane < 8)
                *(ushort8*)(aggC + (size_t)node * 64 + lane * 8) = o;
        }
    } else {
        if (lane < 24) {
            *(ushort8*)(agg + (size_t)node * 256 + 64 + lane * 8) = o;
        } else if (lane >= 48 && lane < 56) {
            const int c2 = lane - 48;
            ushort8 v = *(const ushort8*)(aggC + (size_t)node * 64 + c2 * 8);
            *(ushort8*)(agg + (size_t)node * 256 + c2 * 8) = v;
        }
    }
}

// ---------------- MFMA GEMM ----------------
// C[nrows, BN] = concat_K(A0|A1|A2) @ Bt^T (+bias, +epilogue)
// Bt prepacked in fragment order; A staged via global_load_lds with permuted
// SOURCE index so LDS lands in fragment order -> conflict-free ds_read_b128.
// __launch_bounds__(512, 2): min-waves 6 in round 4 capped VGPR at 40 ->
// accumulator spilled to scratch (399MB WRITE_SIZE, 208us). Keep 2.
// EPI: 0 = bias -> bf16                         (sage linear)
//      1 = bias,lrelu -> bf16                   (prenet hidden, mlp hidden)
//      3 = bf16resid + lrelu -> bf16            (mlp0 final)
//      4 = bf16resid + lrelu -> f32 d_out       (mlp1 final)
//      5 = 1 + keyed store                      (prenet final)
//      6 = 3 + keyed store                      (mlp0 final, keyed for L1)

template<int BN, int EPI>
__global__ __launch_bounds__(512, 2) void k_gemm(
    const u16* __restrict__ A0, int K0,
    const u16* __restrict__ A1, int K1,
    const u16* __restrict__ A2, int K2,
    const u16* __restrict__ Bt,
    const float* __restrict__ bias,
    float* __restrict__ outf,
    u16* __restrict__ outb,
    const u16* __restrict__ resid16,
    u16* __restrict__ keyed,
    int nrows)
{
    constexpr int FN = BN / 64;           // b-frags per wave (4 or 3)
    constexpr int ASZ = 128 * 32;         // A tile elems
    constexpr int BSLOTS = BN * 4;        // 16B slots in B tile
    __shared__ u16 lds[2][ASZ + BN * 32] __attribute__((aligned(16)));

    const int tid = threadIdx.x;
    const int wave = tid >> 6;
    const int lane = tid & 63;
    const int wr = wave >> 2;             // 0..1
    const int wc = wave & 3;              // 0..3
    const int rowbase = blockIdx.x * 128;
    const int Ktot = K0 + K1 + K2;
    const int nk = Ktot >> 5;

    f32x4 zero = {0.f, 0.f, 0.f, 0.f};
    f32x4 acc[4][FN];
    #pragma unroll
    for (int fm = 0; fm < 4; ++fm)
        #pragma unroll
        for (int fn = 0; fn < FN; ++fn)
            acc[fm][fn] = zero;

    auto stage = [&](int buf, int ks) {
        const int k0 = ks * 32;
        const u16* segp; int segoff, segK;
        if (k0 < K0)           { segp = A0; segoff = k0;           segK = K0; }
        else if (k0 < K0 + K1) { segp = A1; segoff = k0 - K0;      segK = K1; }
        else                   { segp = A2; segoff = k0 - K0 - K1; segK = K2; }
        {   // A tile in fragment order: slot tid -> row = wave*16 + (tid&15),
            // k8 = (tid>>4)&3 ; LDS dest linear (wave-uniform base + lane*16)
            int row = ((tid >> 6) << 4) | (tid & 15);
            int grow = rowbase + row;
            if (grow >= nrows) grow = nrows - 1;
            const u16* g = segp + (size_t)grow * segK + segoff + ((tid >> 4) & 3) * 8;
            gload_lds16(g, &lds[buf][wave * 512]);
        }
        #pragma unroll
        for (int it = 0; it < (BSLOTS + 511) / 512; ++it) {
            int slot = it * 512 + tid;
            if (slot < BSLOTS) {          // wave-uniform predicate
                const u16* g = Bt + (size_t)ks * BN * 32 + slot * 8;
                gload_lds16(g, &lds[buf][ASZ + it * 4096 + wave * 512]);
            }
        }
    };

    stage(0, 0);
    __syncthreads();

    const int l15 = lane & 15, l4 = lane >> 4;

    for (int ks = 0; ks < nk; ++ks) {
        const int cur = ks & 1;
        if (ks + 1 < nk) stage(cur ^ 1, ks + 1);
        const u16* la = &lds[cur][0];
        const u16* lb = &lds[cur][ASZ];
        bf16x8 a[4], b[FN];
        #pragma unroll
        for (int fm = 0; fm < 4; ++fm)
            a[fm] = *(const bf16x8*)(la + (wr * 4 + fm) * 512 + lane * 8);
        #pragma unroll
        for (int fn = 0; fn < FN; ++fn)
            b[fn] = *(const bf16x8*)(lb + (wc * FN + fn) * 512 + lane * 8);
        #pragma unroll
        for (int fm = 0; fm < 4; ++fm)
            #pragma unroll
            for (int fn = 0; fn < FN; ++fn)
                acc[fm][fn] = __builtin_amdgcn_mfma_f32_16x16x32_bf16(a[fm], b[fn], acc[fm][fn], 0, 0, 0);
        __syncthreads();
    }

    // epilogue: C/D layout col = lane&15, row = (lane>>4)*4 + r
    const int r0 = rowbase + wr * 64;
    const int c0 = wc * (FN * 16);
    #pragma unroll
    for (int fn = 0; fn < FN; ++fn) {
        const int col = c0 + fn * 16 + l15;
        const float bs = bias[col];
        #pragma unroll
        for (int fm = 0; fm < 4; ++fm) {
            #pragma unroll
            for (int r = 0; r < 4; ++r) {
                const int row = r0 + fm * 16 + l4 * 4 + r;
                if (row < nrows) {
                    float v = acc[fm][fn][r] + bs;
                    if (EPI >= 1) v = (v >= 0.f) ? v : 0.2f * v;
                    if (EPI == 3 || EPI == 4 || EPI == 6) v += b2f(resid16[(size_t)row * BN + col]);
                    u16 hb = f2b(v);
                    if (EPI == 4) outf[(size_t)row * BN + col] = v;
                    else          outb[(size_t)row * BN + col] = hb;
                    if (EPI == 5 || EPI == 6)
                        keyed[(size_t)row * 256 + 64 + col] = keyb(hb);
                }
            }
        }
    }
}

// ---------------- host ----------------

extern "C" void kernel_launch(void* const* d_in, const int* in_sizes, int n_in,
                              void* d_out, int out_size, void* d_ws, size_t ws_size,
                              hipStream_t stream)
{
    (void)in_sizes; (void)n_in; (void)out_size; (void)ws_size;
    const float* node = (const float*)d_in[0];
    const float* conf = (const float*)d_in[1];
    const int* edges  = (const int*)d_in[2];
    const float* pw0  = (const float*)d_in[3];
    const float* pb0  = (const float*)d_in[4];
    const float* pw1  = (const float*)d_in[5];
    const float* pb1  = (const float*)d_in[6];
    const float* W[14];
    for (int i = 0; i < 14; ++i) W[i] = (const float*)d_in[7 + i];
    float* out = (float*)d_out;
    const int* e_src = edges;
    const int* e_dst = edges + N_EDGES;

    // keyed gather mirror [N,256] u16 (51.2MB) aliased onto d_out (76.8MB):
    // last keyed read (k_agg layer 1) precedes the only f32 writer (final GEMM),
    // and every keyed byte read is rewritten each launch (k_prep + epilogues).
    u16* keyed = (u16*)d_out;

    char* w = (char*)d_ws;
    auto alloc = [&](size_t b) { char* p = w; w += (b + 255) & ~(size_t)255; return p; };
    u16* conf16 = (u16*)alloc((size_t)N_NODES * 64 * 2);
    u16* node16 = (u16*)alloc((size_t)N_NODES * 192 * 2);   // prenet input, later h
    u16* x16    = (u16*)alloc((size_t)N_NODES * 192 * 2);   // bf16 residual stream
    u16* agg16  = (u16*)alloc((size_t)N_NODES * 256 * 2);   // agg, then s (in-place)
    u16* aggC   = (u16*)alloc((size_t)N_NODES * 64 * 2);    // saved conf-part max
    int* deg    = (int*)alloc((size_t)N_NODES * 4);
    int* indptr = (int*)alloc((size_t)N_NODES * 4);
    int* cursor = (int*)alloc((size_t)N_NODES * 4);         // becomes end-ptrs
    int* esrc   = (int*)alloc((size_t)N_EDGES * 4);
    int* bsum   = (int*)alloc(4096);
    u16* pw0t   = (u16*)alloc((size_t)192 * 256 * 2);
    u16* pw1t   = (u16*)alloc((size_t)192 * 192 * 2);
    u16 *sB[2], *mw0t[2], *mw1t[2];
    for (int l = 0; l < 2; ++l) {
        sB[l]   = (u16*)alloc((size_t)256 * 512 * 2);
        mw0t[l] = (u16*)alloc((size_t)192 * 256 * 2);
        mw1t[l] = (u16*)alloc((size_t)192 * 192 * 2);
    }

    // fused cast + keyed conf + deg zero
    {
        const int tot = N_NODES * 64 / 4 + N_NODES * 192 / 4 + N_NODES / 4;
        k_prep<<<(tot + 255) / 256, 256, 0, stream>>>(conf, node, conf16, node16, keyed, deg);
    }
    // fused weight packs (fragment order)
    {
        PackArgs pa;
        int off = 0;
        auto seg = [&](int i, const float* a, int K0, const float* b, int K1, int Ncol, u16* dst) {
            int sz = Ncol * (K0 + K1);
            pa.s[i] = {a, b, dst, K0, K1, Ncol, off, off + sz};
            off += sz;
        };
        seg(0, pw0, 256, nullptr, 0, 192, pw0t);
        seg(1, pw1, 192, nullptr, 0, 192, pw1t);
        seg(2, W[0], 256, W[2], 256, 256, sB[0]);
        seg(3, W[3], 256, nullptr, 0, 192, mw0t[0]);
        seg(4, W[5], 192, nullptr, 0, 192, mw1t[0]);
        seg(5, W[7], 256, W[9], 256, 256, sB[1]);
        seg(6, W[10], 256, nullptr, 0, 192, mw0t[1]);
        seg(7, W[12], 192, nullptr, 0, 192, mw1t[1]);
        k_pack<<<(off + 255) / 256, 256, 0, stream>>>(pa, off);
    }
    // CSR
    k_count<<<(N_EDGES + 255) / 256, 256, 0, stream>>>(e_dst, deg);
    int nb = (N_NODES + 2047) / 2048;
    k_scan1<<<nb, 512, 0, stream>>>(deg, indptr, bsum, N_NODES);
    k_scan2<<<1, 64, 0, stream>>>(bsum, nb);
    k_scan3<<<(N_NODES + 255) / 256, 256, 0, stream>>>(indptr, bsum, cursor, N_NODES);
    k_scatter<<<(N_EDGES + 255) / 256, 256, 0, stream>>>(e_src, e_dst, cursor, esrc);
    // cursor now holds per-node END pointers (indptr + deg)

    const int gblk = (N_NODES + 127) / 128;   // 782
    // prenet: x16 = lrelu(lrelu([conf|node]@w0+b0)@w1 + b1); final also fills keyed x
    k_gemm<192, 1><<<gblk, 512, 0, stream>>>(conf16, 64, node16, 192, nullptr, 0,
                                             pw0t, pb0, nullptr, x16, nullptr, nullptr, N_NODES);
    k_gemm<192, 5><<<gblk, 512, 0, stream>>>(x16, 192, nullptr, 0, nullptr, 0,
                                             pw1t, pb1, nullptr, x16, nullptr, keyed, N_NODES);
    for (int l = 0; l < 2; ++l) {
        if (l == 0)
            k_agg<32><<<N_NODES / 4, 256, 0, stream>>>(keyed, indptr, deg, cursor, esrc, agg16, aggC);
        else
            k_agg<24><<<N_NODES / 4, 256, 0, stream>>>(keyed, indptr, deg, cursor, esrc, agg16, aggC);
        // s = agg@wl + bl + [conf|x]@wr   (K=512 fused; in-place over agg16)
        k_gemm<256, 0><<<gblk, 512, 0, stream>>>(agg16, 256, conf16, 64, x16, 192,
                                                 sB[l], W[7*l+1], nullptr, agg16, nullptr, nullptr, N_NODES);
        // h = lrelu(s@mw0 + mb0)
        k_gemm<192, 1><<<gblk, 512, 0, stream>>>(agg16, 256, nullptr, 0, nullptr, 0,
                                                 mw0t[l], W[7*l+4], nullptr, node16, nullptr, nullptr, N_NODES);
        // x = x + lrelu(h@mw1 + mb1)
        if (l == 0)
            k_gemm<192, 6><<<gblk, 512, 0, stream>>>(node16, 192, nullptr, 0, nullptr, 0,
                                                     mw1t[l], W[7*l+6], nullptr, x16, x16, keyed, N_NODES);
        else
            k_gemm<192, 4><<<gblk, 512, 0, stream>>>(node16, 192, nullptr, 0, nullptr, 0,
                                                     mw1t[l], W[7*l+6], out, nullptr, x16, nullptr, N_NODES);
    }
}

// Round 6
// 522.331 us; speedup vs baseline: 1.7348x; 1.1395x over previous
//
#include <hip/hip_runtime.h>
#include <stdint.h>

#define N_NODES 100000
#define N_EDGES 800000

typedef unsigned short u16;
typedef __attribute__((ext_vector_type(8))) short bf16x8;
typedef __attribute__((ext_vector_type(8))) unsigned short ushort8;
typedef __attribute__((ext_vector_type(4))) float f32x4;
typedef __attribute__((ext_vector_type(4))) int i32x4;
typedef __attribute__((ext_vector_type(4))) unsigned int u32x4;

struct alignas(8) U16x4 { u16 x, y, z, w; };

__device__ __forceinline__ u16 f2b(float f) {
    union { float f; unsigned u; } x; x.f = f;
    unsigned r = (x.u + 0x7FFFu + ((x.u >> 16) & 1u)) >> 16;
    return (u16)r;
}
__device__ __forceinline__ float b2f(u16 h) {
    union { unsigned u; float f; } x; x.u = ((unsigned)h) << 16;
    return x.f;
}
// monotone bf16 -> u16 key: float order == unsigned order
__device__ __forceinline__ u16 keyb(u16 h) {
    u16 m = (u16)((short)h >> 15);
    return (u16)(h ^ (0x8000u | (m & 0x7FFFu)));
}
__device__ __forceinline__ u16 unkey(u16 k) {
    u16 m = (u16)((short)k >> 15);
    return (u16)(k ^ (0x8000u | (~m & 0x7FFFu)));
}
__device__ __forceinline__ unsigned pkmax(unsigned a, unsigned b) {
    unsigned d;
    asm("v_pk_max_u16 %0, %1, %2" : "=v"(d) : "v"(a), "v"(b));
    return d;
}
__device__ __forceinline__ u32x4 pkmax4(u32x4 a, u32x4 b) {
    u32x4 r;
    r.x = pkmax(a.x, b.x); r.y = pkmax(a.y, b.y);
    r.z = pkmax(a.z, b.z); r.w = pkmax(a.w, b.w);
    return r;
}

__device__ __forceinline__ void gload_lds16(const void* g, void* l) {
    __builtin_amdgcn_global_load_lds(
        (const __attribute__((address_space(1))) char*)(uintptr_t)g,
        (__attribute__((address_space(3))) char*)(uintptr_t)l,
        16, 0, 0);
}

// ---------------- fused input cast + keyed conf + deg zeroing ----------------

__global__ void k_prep(const float* __restrict__ conf, const float* __restrict__ node,
                       u16* __restrict__ conf16, u16* __restrict__ node16,
                       u16* __restrict__ keyed, int* __restrict__ deg) {
    const int c4 = N_NODES * 64 / 4;
    const int n4 = N_NODES * 192 / 4;
    int i = blockIdx.x * blockDim.x + threadIdx.x;
    if (i < c4) {
        float4 v = ((const float4*)conf)[i];
        U16x4 o; o.x = f2b(v.x); o.y = f2b(v.y); o.z = f2b(v.z); o.w = f2b(v.w);
        ((U16x4*)conf16)[i] = o;
        U16x4 ko; ko.x = keyb(o.x); ko.y = keyb(o.y); ko.z = keyb(o.z); ko.w = keyb(o.w);
        int n = i >> 4;
        ((U16x4*)keyed)[n * 64 + (i & 15)] = ko;
    } else if (i < c4 + n4) {
        float4 v = ((const float4*)node)[i - c4];
        U16x4 o; o.x = f2b(v.x); o.y = f2b(v.y); o.z = f2b(v.z); o.w = f2b(v.w);
        ((U16x4*)node16)[i - c4] = o;
    } else if (i < c4 + n4 + N_NODES / 4) {
        i32x4 z = {0, 0, 0, 0};
        ((i32x4*)deg)[i - c4 - n4] = z;
    }
}

// ---------------- fused weight packing (fragment order) ----------------

struct PackSeg { const float* a; const float* b; u16* dst; int K0, K1, Ncol, beg, end; };
struct PackArgs { PackSeg s[8]; };

__global__ void k_pack(PackArgs p, int total) {
    int idx = blockIdx.x * blockDim.x + threadIdx.x;
    if (idx >= total) return;
    #pragma unroll
    for (int si = 0; si < 8; ++si) {
        if (idx >= p.s[si].beg && idx < p.s[si].end) {
            int li = idx - p.s[si].beg;
            int Ncol = p.s[si].Ncol, K0 = p.s[si].K0;
            int kq = li & 7;
            int t = li >> 3;
            int c15 = t & 15; t >>= 4;
            int k8 = t & 3;  t >>= 2;
            int nb = Ncol >> 4;
            int cb = t % nb;
            int ks = t / nb;
            int col = cb * 16 + c15;
            int k = ks * 32 + k8 * 8 + kq;
            float v = (k < K0) ? p.s[si].a[(size_t)k * Ncol + col]
                               : p.s[si].b[(size_t)(k - K0) * Ncol + col];
            p.s[si].dst[li] = f2b(v);
        }
    }
}

// ---------------- CSR build ----------------

__global__ void k_count(const int* __restrict__ dst, int* __restrict__ deg) {
    int e = blockIdx.x * blockDim.x + threadIdx.x;
    if (e < N_EDGES) atomicAdd(&deg[dst[e]], 1);
}

__global__ void k_scan1(const int* __restrict__ deg, int* __restrict__ excl,
                        int* __restrict__ bsum, int n) {
    __shared__ int sh[512];
    int t = threadIdx.x;
    int base = blockIdx.x * 2048 + t * 4;
    int v0 = (base + 0 < n) ? deg[base + 0] : 0;
    int v1 = (base + 1 < n) ? deg[base + 1] : 0;
    int v2 = (base + 2 < n) ? deg[base + 2] : 0;
    int v3 = (base + 3 < n) ? deg[base + 3] : 0;
    int tot = v0 + v1 + v2 + v3;
    sh[t] = tot;
    __syncthreads();
    for (int off = 1; off < 512; off <<= 1) {
        int x = (t >= off) ? sh[t - off] : 0;
        __syncthreads();
        sh[t] += x;
        __syncthreads();
    }
    int run = sh[t] - tot;
    if (base + 0 < n) excl[base + 0] = run; run += v0;
    if (base + 1 < n) excl[base + 1] = run; run += v1;
    if (base + 2 < n) excl[base + 2] = run; run += v2;
    if (base + 3 < n) excl[base + 3] = run;
    if (t == 511) bsum[blockIdx.x] = sh[t];
}

__global__ void k_scan2(int* __restrict__ bsum, int nb) {
    __shared__ int sh[64];
    int t = threadIdx.x;
    int v = (t < nb) ? bsum[t] : 0;
    sh[t] = v;
    __syncthreads();
    for (int off = 1; off < 64; off <<= 1) {
        int x = (t >= off) ? sh[t - off] : 0;
        __syncthreads();
        sh[t] += x;
        __syncthreads();
    }
    if (t < nb) bsum[t] = sh[t] - v;
}

__global__ void k_scan3(int* __restrict__ excl, const int* __restrict__ bsum,
                        int* __restrict__ cursor, int n) {
    int i = blockIdx.x * blockDim.x + threadIdx.x;
    if (i < n) {
        int v = excl[i] + bsum[i >> 11];
        excl[i] = v;
        cursor[i] = v;
    }
}

__global__ void k_scatter(const int* __restrict__ src, const int* __restrict__ dst,
                          int* __restrict__ cursor, int* __restrict__ esrc) {
    int e = blockIdx.x * blockDim.x + threadIdx.x;
    if (e < N_EDGES) {
        int p = atomicAdd(&cursor[dst[e]], 1);
        esrc[p] = src[e];
    }
}

// ---------------- segment-max aggregation (keyed u16 domain) ----------------

template<int CHUNKS>
__global__ __launch_bounds__(256) void k_agg(
    const u16* __restrict__ keyed,
    const int* __restrict__ indptr, const int* __restrict__ deg,
    const int* __restrict__ iend, const int* __restrict__ esrc,
    u16* __restrict__ agg, u16* __restrict__ aggC) {
    __shared__ int se[512];
    __shared__ int sinfo[2];
    const int b4 = blockIdx.x * 4;
    if (threadIdx.x == 0) {
        sinfo[0] = indptr[b4];
        sinfo[1] = iend[b4 + 3];
    }
    __syncthreads();
    const int sbase = sinfo[0];
    const int slen = sinfo[1] - sbase;
    const bool useLds = slen <= 512;
    if (useLds) {
        for (int i = threadIdx.x; i < slen; i += 256) se[i] = esrc[sbase + i];
    }
    __syncthreads();

    const int node = b4 + (threadIdx.x >> 6);
    const int lane = threadIdx.x & 63;
    constexpr int ACTIVE = (CHUNKS == 32) ? 64 : 48;
    const int e_sub = (CHUNKS == 32) ? (lane >> 5) : (lane >= 24 ? 1 : 0);
    int ch = lane - e_sub * CHUNKS;
    if (ch < 0 || ch >= CHUNKS) ch = 0;
    const int start = indptr[node];
    const int d = deg[node];
    const u16* bp = keyed + ((CHUNKS == 32) ? 0 : 64) + ch * 8;

    u32x4 m = {0u, 0u, 0u, 0u};

    if (lane < ACTIVE && d > 0) {
        const int rounds = (d + 7) >> 3;
        const int lbase = start - sbase;
        for (int rr = 0; rr < rounds; ++rr) {
            const int b0 = rr * 8 + e_sub;
            const int dm1 = d - 1;
            int i0 = min(b0, dm1), i1 = min(b0 + 2, dm1);
            int i2 = min(b0 + 4, dm1), i3 = min(b0 + 6, dm1);
            int s0, s1, s2, s3;
            if (useLds) {
                s0 = se[lbase + i0]; s1 = se[lbase + i1];
                s2 = se[lbase + i2]; s3 = se[lbase + i3];
            } else {
                s0 = esrc[start + i0]; s1 = esrc[start + i1];
                s2 = esrc[start + i2]; s3 = esrc[start + i3];
            }
            u32x4 v0 = *(const u32x4*)(bp + (size_t)s0 * 256);
            u32x4 v1 = *(const u32x4*)(bp + (size_t)s1 * 256);
            u32x4 v2 = *(const u32x4*)(bp + (size_t)s2 * 256);
            u32x4 v3 = *(const u32x4*)(bp + (size_t)s3 * 256);
            m = pkmax4(m, pkmax4(pkmax4(v0, v1), pkmax4(v2, v3)));
        }
    }

    if (CHUNKS == 32) {
        m.x = pkmax(m.x, __shfl_xor(m.x, 32, 64));
        m.y = pkmax(m.y, __shfl_xor(m.y, 32, 64));
        m.z = pkmax(m.z, __shfl_xor(m.z, 32, 64));
        m.w = pkmax(m.w, __shfl_xor(m.w, 32, 64));
    } else {
        m.x = pkmax(m.x, __shfl(m.x, lane + 24, 64));
        m.y = pkmax(m.y, __shfl(m.y, lane + 24, 64));
        m.z = pkmax(m.z, __shfl(m.z, lane + 24, 64));
        m.w = pkmax(m.w, __shfl(m.w, lane + 24, 64));
    }

    unsigned wv[4] = {m.x, m.y, m.z, m.w};
    ushort8 o;
    #pragma unroll
    for (int j = 0; j < 4; ++j) {
        u16 klo = (u16)(wv[j] & 0xFFFFu), khi = (u16)(wv[j] >> 16);
        o[2 * j]     = (d > 0) ? unkey(klo) : (u16)0;
        o[2 * j + 1] = (d > 0) ? unkey(khi) : (u16)0;
    }

    if (CHUNKS == 32) {
        if (lane < 32) {
            *(ushort8*)(agg + (size_t)node * 256 + lane * 8) = o;
            if (lane < 8)
                *(ushort8*)(aggC + (size_t)node * 64 + lane * 8) = o;
        }
    } else {
        if (lane < 24) {
            *(ushort8*)(agg + (size_t)node * 256 + 64 + lane * 8) = o;
        } else if (lane >= 48 && lane < 56) {
            const int c2 = lane - 48;
            ushort8 v = *(const ushort8*)(aggC + (size_t)node * 64 + c2 * 8);
            *(ushort8*)(agg + (size_t)node * 256 + c2 * 8) = v;
        }
    }
}

// ---------------- MFMA GEMM (sage only): C = concat(A0|A1|A2) @ Bt^T + bias ----
// Staging pointers are hoisted/incremental (the segment switch is a rare
// wave-uniform branch) -- round 5's per-k-step address recompute was ~60
// VALU/thread/step. Fragment-order layouts as before (conflict-free ds_read).

template<int BN>
__global__ __launch_bounds__(512, 2) void k_gemm(
    const u16* __restrict__ A0, int K0,
    const u16* __restrict__ A1, int K1,
    const u16* __restrict__ A2, int K2,
    const u16* __restrict__ Bt,
    const float* __restrict__ bias,
    u16* __restrict__ outb,
    int nrows)
{
    constexpr int FN = BN / 64;
    constexpr int ASZ = 128 * 32;
    __shared__ u16 lds[2][ASZ + BN * 32] __attribute__((aligned(16)));

    const int tid = threadIdx.x;
    const int wave = tid >> 6;
    const int lane = tid & 63;
    const int wr = wave >> 2;
    const int wc = wave & 3;
    const int rowbase = blockIdx.x * 128;
    const int nk = (K0 + K1 + K2) >> 5;

    // hoisted staging state
    const int arow = ((tid >> 6) << 4) | (tid & 15);
    int grow = rowbase + arow; if (grow >= nrows) grow = nrows - 1;
    const int ak8 = (tid >> 4) & 3;
    const u16* segp[3] = {A0, A1, A2};
    const int segK[3] = {K0, K1, K2};
    int seg = 0;
    const u16* gA = segp[0] + (size_t)grow * segK[0] + ak8 * 8;
    int segleft = segK[0] >> 5;
    const u16* gB0 = Bt + (size_t)tid * 8;
    const u16* gB1 = Bt + (size_t)(512 + tid) * 8;
    const int wb = wave * 512;

    auto adv = [&]() {
        gA += 32;
        if (--segleft == 0) {
            while (seg < 2) {
                ++seg;
                if (segK[seg] > 0) {
                    gA = segp[seg] + (size_t)grow * segK[seg] + ak8 * 8;
                    segleft = segK[seg] >> 5;
                    break;
                }
            }
        }
        gB0 += BN * 32;
        gB1 += BN * 32;
    };
    auto stage = [&](int buf) {
        gload_lds16(gA, &lds[buf][wb]);
        gload_lds16(gB0, &lds[buf][ASZ + wb]);
        if constexpr (BN == 256) {
            gload_lds16(gB1, &lds[buf][ASZ + 4096 + wb]);
        } else {
            if (tid < 256) gload_lds16(gB1, &lds[buf][ASZ + 4096 + wb]);
        }
    };

    f32x4 zero = {0.f, 0.f, 0.f, 0.f};
    f32x4 acc[4][FN];
    #pragma unroll
    for (int fm = 0; fm < 4; ++fm)
        #pragma unroll
        for (int fn = 0; fn < FN; ++fn)
            acc[fm][fn] = zero;

    stage(0); adv();
    __syncthreads();

    const int l15 = lane & 15, l4 = lane >> 4;

    for (int ks = 0; ks < nk; ++ks) {
        const int cur = ks & 1;
        if (ks + 1 < nk) { stage(cur ^ 1); adv(); }
        const u16* la = &lds[cur][0];
        const u16* lb = &lds[cur][ASZ];
        bf16x8 a[4], b[FN];
        #pragma unroll
        for (int fm = 0; fm < 4; ++fm)
            a[fm] = *(const bf16x8*)(la + (wr * 4 + fm) * 512 + lane * 8);
        #pragma unroll
        for (int fn = 0; fn < FN; ++fn)
            b[fn] = *(const bf16x8*)(lb + (wc * FN + fn) * 512 + lane * 8);
        #pragma unroll
        for (int fm = 0; fm < 4; ++fm)
            #pragma unroll
            for (int fn = 0; fn < FN; ++fn)
                acc[fm][fn] = __builtin_amdgcn_mfma_f32_16x16x32_bf16(a[fm], b[fn], acc[fm][fn], 0, 0, 0);
        __syncthreads();
    }

    const int r0 = rowbase + wr * 64;
    const int c0 = wc * (FN * 16);
    #pragma unroll
    for (int fn = 0; fn < FN; ++fn) {
        const int col = c0 + fn * 16 + l15;
        const float bs = bias[col];
        #pragma unroll
        for (int fm = 0; fm < 4; ++fm) {
            #pragma unroll
            for (int r = 0; r < 4; ++r) {
                const int row = r0 + fm * 16 + l4 * 4 + r;
                if (row < nrows)
                    outb[(size_t)row * BN + col] = f2b(acc[fm][fn][r] + bs);
            }
        }
    }
}

// ---------------- fused double-GEMM ----------------
// Phase 1: h = lrelu(concat(A0|A1) @ B1t^T + bias1)   [128 x 192, kept in LDS
//          in A-fragment order -- no HBM round-trip]
// Phase 2: y = epilogue( h @ B2t^T + bias2 )          [B2 (192x192) lives in
//          18 bf16x8 REGISTERS; phase 2 has zero staging and zero barriers]
// EPI: 4 = lrelu, +resid -> f32 outf    (mlp1 final)
//      5 = lrelu -> bf16 outb + keyed   (prenet final)
//      6 = lrelu, +resid -> bf16 outb + keyed (mlp0 final)

template<int EPI>
__global__ __launch_bounds__(512, 2) void k_fused(
    const u16* __restrict__ A0, int K0,
    const u16* __restrict__ A1, int K1,
    const u16* __restrict__ B1t, const float* __restrict__ bias1,
    const u16* __restrict__ B2t, const float* __restrict__ bias2,
    float* __restrict__ outf, u16* __restrict__ outb,
    const u16* __restrict__ resid16, u16* __restrict__ keyed,
    int nrows)
{
    // LDS layout (u16 units): A dbuf [0,4096)+[4096,8192); B1 dbuf
    // [8192,14336)+[14336,20480); h [0,24576) overlays them after phase 1.
    __shared__ u16 lds[24576] __attribute__((aligned(16)));

    const int tid = threadIdx.x;
    const int wave = tid >> 6;
    const int lane = tid & 63;
    const int wr = wave >> 2;
    const int wc = wave & 3;
    const int l15 = lane & 15, l4 = lane >> 4;
    const int rowbase = blockIdx.x * 128;
    const int nk1 = (K0 + K1) >> 5;

    const int arow = ((tid >> 6) << 4) | (tid & 15);
    int grow = rowbase + arow; if (grow >= nrows) grow = nrows - 1;
    const int ak8 = (tid >> 4) & 3;
    const u16* gA = A0 + (size_t)grow * K0 + ak8 * 8;
    int segleft = K0 >> 5;
    const u16* gB0 = B1t + (size_t)tid * 8;
    const u16* gB1 = B1t + (size_t)(512 + tid) * 8;
    const int wb = wave * 512;

    auto adv = [&]() {
        gA += 32;
        if (--segleft == 0 && K1 > 0) {
            gA = A1 + (size_t)grow * K1 + ak8 * 8;
            segleft = K1 >> 5;   // only one switch ever needed (2 segments)
        }
        gB0 += 6144;
        gB1 += 6144;
    };
    auto stage = [&](int buf) {
        gload_lds16(gA, &lds[buf * 4096 + wb]);
        gload_lds16(gB0, &lds[8192 + buf * 6144 + wb]);
        if (tid < 256) gload_lds16(gB1, &lds[8192 + buf * 6144 + 4096 + wb]);
    };

    f32x4 zero = {0.f, 0.f, 0.f, 0.f};
    f32x4 acc[4][3];
    #pragma unroll
    for (int fm = 0; fm < 4; ++fm)
        #pragma unroll
        for (int fn = 0; fn < 3; ++fn)
            acc[fm][fn] = zero;

    stage(0); adv();
    __syncthreads();

    for (int ks = 0; ks < nk1; ++ks) {
        const int cur = ks & 1;
        if (ks + 1 < nk1) { stage(cur ^ 1); adv(); }
        const u16* la = &lds[cur * 4096];
        const u16* lb = &lds[8192 + cur * 6144];
        bf16x8 a[4], b[3];
        #pragma unroll
        for (int fm = 0; fm < 4; ++fm)
            a[fm] = *(const bf16x8*)(la + (wr * 4 + fm) * 512 + lane * 8);
        #pragma unroll
        for (int fn = 0; fn < 3; ++fn)
            b[fn] = *(const bf16x8*)(lb + (wc * 3 + fn) * 512 + lane * 8);
        #pragma unroll
        for (int fm = 0; fm < 4; ++fm)
            #pragma unroll
            for (int fn = 0; fn < 3; ++fn)
                acc[fm][fn] = __builtin_amdgcn_mfma_f32_16x16x32_bf16(a[fm], b[fn], acc[fm][fn], 0, 0, 0);
        __syncthreads();
    }

    // phase-1 epilogue: lrelu(acc + bias1) -> h in LDS, A-fragment order:
    // h(row,c) at (c>>5)*4096 + (row>>4)*512 + ((c>>3)&3)*128 + (row&15)*8 + (c&7)
    {
        const int c0 = wc * 48;
        #pragma unroll
        for (int fn = 0; fn < 3; ++fn) {
            const int c = c0 + fn * 16 + l15;
            const float bs = bias1[c];
            const int coff = (c >> 5) * 4096 + ((c >> 3) & 3) * 128 + (c & 7);
            #pragma unroll
            for (int fm = 0; fm < 4; ++fm) {
                const int rb = wr * 4 + fm;
                #pragma unroll
                for (int rr = 0; rr < 4; ++rr) {
                    const int r16 = l4 * 4 + rr;
                    float v = acc[fm][fn][rr] + bs;
                    v = (v >= 0.f) ? v : 0.2f * v;
                    lds[coff + rb * 512 + r16 * 8] = f2b(v);
                }
            }
        }
    }
    __syncthreads();

    // phase 2: B2 into registers (L2-hot, one-time), then pure ds_read+MFMA
    bf16x8 breg[18];
    #pragma unroll
    for (int ks = 0; ks < 6; ++ks)
        #pragma unroll
        for (int fn = 0; fn < 3; ++fn)
            breg[ks * 3 + fn] = *(const bf16x8*)(B2t + (size_t)(ks * 12 + wc * 3 + fn) * 512 + lane * 8);

    f32x4 acc2[4][3];
    #pragma unroll
    for (int fm = 0; fm < 4; ++fm)
        #pragma unroll
        for (int fn = 0; fn < 3; ++fn)
            acc2[fm][fn] = zero;

    #pragma unroll
    for (int ks = 0; ks < 6; ++ks) {
        bf16x8 a2[4];
        #pragma unroll
        for (int fm = 0; fm < 4; ++fm)
            a2[fm] = *(const bf16x8*)(&lds[ks * 4096 + (wr * 4 + fm) * 512 + lane * 8]);
        #pragma unroll
        for (int fm = 0; fm < 4; ++fm)
            #pragma unroll
            for (int fn = 0; fn < 3; ++fn)
                acc2[fm][fn] = __builtin_amdgcn_mfma_f32_16x16x32_bf16(a2[fm], breg[ks * 3 + fn], acc2[fm][fn], 0, 0, 0);
    }

    // phase-2 epilogue
    const int r0 = rowbase + wr * 64;
    const int c0 = wc * 48;
    #pragma unroll
    for (int fn = 0; fn < 3; ++fn) {
        const int col = c0 + fn * 16 + l15;
        const float bs = bias2[col];
        #pragma unroll
        for (int fm = 0; fm < 4; ++fm) {
            #pragma unroll
            for (int r = 0; r < 4; ++r) {
                const int row = r0 + fm * 16 + l4 * 4 + r;
                if (row < nrows) {
                    float v = acc2[fm][fn][r] + bs;
                    v = (v >= 0.f) ? v : 0.2f * v;
                    if (EPI == 4 || EPI == 6) v += b2f(resid16[(size_t)row * 192 + col]);
                    if (EPI == 4) {
                        outf[(size_t)row * 192 + col] = v;
                    } else {
                        u16 hb = f2b(v);
                        outb[(size_t)row * 192 + col] = hb;
                        keyed[(size_t)row * 256 + 64 + col] = keyb(hb);
                    }
                }
            }
        }
    }
}

// ---------------- host ----------------

extern "C" void kernel_launch(void* const* d_in, const int* in_sizes, int n_in,
                              void* d_out, int out_size, void* d_ws, size_t ws_size,
                              hipStream_t stream)
{
    (void)in_sizes; (void)n_in; (void)out_size; (void)ws_size;
    const float* node = (const float*)d_in[0];
    const float* conf = (const float*)d_in[1];
    const int* edges  = (const int*)d_in[2];
    const float* pw0  = (const float*)d_in[3];
    const float* pb0  = (const float*)d_in[4];
    const float* pw1  = (const float*)d_in[5];
    const float* pb1  = (const float*)d_in[6];
    const float* W[14];
    for (int i = 0; i < 14; ++i) W[i] = (const float*)d_in[7 + i];
    float* out = (float*)d_out;
    const int* e_src = edges;
    const int* e_dst = edges + N_EDGES;

    // keyed gather mirror [N,256] u16 aliased onto d_out (see round 3 note)
    u16* keyed = (u16*)d_out;

    char* w = (char*)d_ws;
    auto alloc = [&](size_t b) { char* p = w; w += (b + 255) & ~(size_t)255; return p; };
    u16* conf16 = (u16*)alloc((size_t)N_NODES * 64 * 2);
    u16* node16 = (u16*)alloc((size_t)N_NODES * 192 * 2);
    u16* x16    = (u16*)alloc((size_t)N_NODES * 192 * 2);
    u16* agg16  = (u16*)alloc((size_t)N_NODES * 256 * 2);   // agg, then s (in-place)
    u16* aggC   = (u16*)alloc((size_t)N_NODES * 64 * 2);
    int* deg    = (int*)alloc((size_t)N_NODES * 4);
    int* indptr = (int*)alloc((size_t)N_NODES * 4);
    int* cursor = (int*)alloc((size_t)N_NODES * 4);
    int* esrc   = (int*)alloc((size_t)N_EDGES * 4);
    int* bsum   = (int*)alloc(4096);
    u16* pw0t   = (u16*)alloc((size_t)192 * 256 * 2);
    u16* pw1t   = (u16*)alloc((size_t)192 * 192 * 2);
    u16 *sB[2], *mw0t[2], *mw1t[2];
    for (int l = 0; l < 2; ++l) {
        sB[l]   = (u16*)alloc((size_t)256 * 512 * 2);
        mw0t[l] = (u16*)alloc((size_t)192 * 256 * 2);
        mw1t[l] = (u16*)alloc((size_t)192 * 192 * 2);
    }

    {
        const int tot = N_NODES * 64 / 4 + N_NODES * 192 / 4 + N_NODES / 4;
        k_prep<<<(tot + 255) / 256, 256, 0, stream>>>(conf, node, conf16, node16, keyed, deg);
    }
    {
        PackArgs pa;
        int off = 0;
        auto seg = [&](int i, const float* a, int K0, const float* b, int K1, int Ncol, u16* dst) {
            int sz = Ncol * (K0 + K1);
            pa.s[i] = {a, b, dst, K0, K1, Ncol, off, off + sz};
            off += sz;
        };
        seg(0, pw0, 256, nullptr, 0, 192, pw0t);
        seg(1, pw1, 192, nullptr, 0, 192, pw1t);
        seg(2, W[0], 256, W[2], 256, 256, sB[0]);
        seg(3, W[3], 256, nullptr, 0, 192, mw0t[0]);
        seg(4, W[5], 192, nullptr, 0, 192, mw1t[0]);
        seg(5, W[7], 256, W[9], 256, 256, sB[1]);
        seg(6, W[10], 256, nullptr, 0, 192, mw0t[1]);
        seg(7, W[12], 192, nullptr, 0, 192, mw1t[1]);
        k_pack<<<(off + 255) / 256, 256, 0, stream>>>(pa, off);
    }
    k_count<<<(N_EDGES + 255) / 256, 256, 0, stream>>>(e_dst, deg);
    int nb = (N_NODES + 2047) / 2048;
    k_scan1<<<nb, 512, 0, stream>>>(deg, indptr, bsum, N_NODES);
    k_scan2<<<1, 64, 0, stream>>>(bsum, nb);
    k_scan3<<<(N_NODES + 255) / 256, 256, 0, stream>>>(indptr, bsum, cursor, N_NODES);
    k_scatter<<<(N_EDGES + 255) / 256, 256, 0, stream>>>(e_src, e_dst, cursor, esrc);

    const int gblk = (N_NODES + 127) / 128;   // 782
    // prenet fused: x = lrelu(lrelu([conf|node]@w0+b0)@w1+b1) -> x16 + keyed
    k_fused<5><<<gblk, 512, 0, stream>>>(conf16, 64, node16, 192,
                                         pw0t, pb0, pw1t, pb1,
                                         nullptr, x16, nullptr, keyed, N_NODES);
    for (int l = 0; l < 2; ++l) {
        if (l == 0)
            k_agg<32><<<N_NODES / 4, 256, 0, stream>>>(keyed, indptr, deg, cursor, esrc, agg16, aggC);
        else
            k_agg<24><<<N_NODES / 4, 256, 0, stream>>>(keyed, indptr, deg, cursor, esrc, agg16, aggC);
        // s = agg@wl + bl + [conf|x]@wr   (K=512 fused concat; in-place agg16)
        k_gemm<256><<<gblk, 512, 0, stream>>>(agg16, 256, conf16, 64, x16, 192,
                                              sB[l], W[7*l+1], agg16, N_NODES);
        // fused mlp: x = x + lrelu(lrelu(s@mw0+mb0)@mw1+mb1)
        if (l == 0)
            k_fused<6><<<gblk, 512, 0, stream>>>(agg16, 256, nullptr, 0,
                                                 mw0t[0], W[4], mw1t[0], W[6],
                                                 nullptr, x16, x16, keyed, N_NODES);
        else
            k_fused<4><<<gblk, 512, 0, stream>>>(agg16, 256, nullptr, 0,
                                                 mw0t[1], W[11], mw1t[1], W[13],
                                                 out, nullptr, x16, nullptr, N_NODES);
    }
}

// Round 8
// 444.094 us; speedup vs baseline: 2.0404x; 1.1762x over previous
//
#include <hip/hip_runtime.h>
#include <stdint.h>

#define N_NODES 100000
#define N_EDGES 800000

typedef unsigned short u16;
typedef __attribute__((ext_vector_type(8))) short bf16x8;
typedef __attribute__((ext_vector_type(8))) unsigned short ushort8;
typedef __attribute__((ext_vector_type(4))) float f32x4;
typedef __attribute__((ext_vector_type(4))) int i32x4;
typedef __attribute__((ext_vector_type(4))) unsigned int u32x4;

struct alignas(8) U16x4 { u16 x, y, z, w; };

__device__ __forceinline__ u16 f2b(float f) {
    union { float f; unsigned u; } x; x.f = f;
    unsigned r = (x.u + 0x7FFFu + ((x.u >> 16) & 1u)) >> 16;
    return (u16)r;
}
__device__ __forceinline__ float b2f(u16 h) {
    union { unsigned u; float f; } x; x.u = ((unsigned)h) << 16;
    return x.f;
}
// monotone bf16 -> u16 key: float order == unsigned order
__device__ __forceinline__ u16 keyb(u16 h) {
    u16 m = (u16)((short)h >> 15);
    return (u16)(h ^ (0x8000u | (m & 0x7FFFu)));
}
__device__ __forceinline__ u16 unkey(u16 k) {
    u16 m = (u16)((short)k >> 15);
    return (u16)(k ^ (0x8000u | (~m & 0x7FFFu)));
}
__device__ __forceinline__ unsigned pkmax(unsigned a, unsigned b) {
    unsigned d;
    asm("v_pk_max_u16 %0, %1, %2" : "=v"(d) : "v"(a), "v"(b));
    return d;
}
__device__ __forceinline__ u32x4 pkmax4(u32x4 a, u32x4 b) {
    u32x4 r;
    r.x = pkmax(a.x, b.x); r.y = pkmax(a.y, b.y);
    r.z = pkmax(a.z, b.z); r.w = pkmax(a.w, b.w);
    return r;
}

__device__ __forceinline__ void gload_lds16(const void* g, void* l) {
    __builtin_amdgcn_global_load_lds(
        (const __attribute__((address_space(1))) char*)(uintptr_t)g,
        (__attribute__((address_space(3))) char*)(uintptr_t)l,
        16, 0, 0);
}

// Epilogue staging images: plain row-major with +8 col pad (bijective!).
// Round 7's fragment-nested "pad" overflowed its enclosing stride
// (3*136+127=535 > 512) -> address collisions -> absmax 3.15. Row-major
// padded strides (136/200 u16 = 272/400 B, both x16B) keep vector alignment
// and rotate banks by 4 per row.
__device__ __forceinline__ int simgG(int row, int col) { return row * 136 + col; } // 128 cols
__device__ __forceinline__ int simgF(int row, int col) { return row * 200 + col; } // 192 cols

// ---------------- fused input cast + keyed conf + deg zeroing ----------------

__global__ void k_prep(const float* __restrict__ conf, const float* __restrict__ node,
                       u16* __restrict__ conf16, u16* __restrict__ node16,
                       u16* __restrict__ keyed, int* __restrict__ deg) {
    const int c4 = N_NODES * 64 / 4;
    const int n4 = N_NODES * 192 / 4;
    int i = blockIdx.x * blockDim.x + threadIdx.x;
    if (i < c4) {
        float4 v = ((const float4*)conf)[i];
        U16x4 o; o.x = f2b(v.x); o.y = f2b(v.y); o.z = f2b(v.z); o.w = f2b(v.w);
        ((U16x4*)conf16)[i] = o;
        U16x4 ko; ko.x = keyb(o.x); ko.y = keyb(o.y); ko.z = keyb(o.z); ko.w = keyb(o.w);
        int n = i >> 4;
        ((U16x4*)keyed)[n * 64 + (i & 15)] = ko;
    } else if (i < c4 + n4) {
        float4 v = ((const float4*)node)[i - c4];
        U16x4 o; o.x = f2b(v.x); o.y = f2b(v.y); o.z = f2b(v.z); o.w = f2b(v.w);
        ((U16x4*)node16)[i - c4] = o;
    } else if (i < c4 + n4 + N_NODES / 4) {
        i32x4 z = {0, 0, 0, 0};
        ((i32x4*)deg)[i - c4 - n4] = z;
    }
}

// ---------------- fused weight packing (fragment order) ----------------

struct PackSeg { const float* a; const float* b; u16* dst; int K0, K1, Ncol, beg, end; };
struct PackArgs { PackSeg s[8]; };

__global__ void k_pack(PackArgs p, int total) {
    int idx = blockIdx.x * blockDim.x + threadIdx.x;
    if (idx >= total) return;
    #pragma unroll
    for (int si = 0; si < 8; ++si) {
        if (idx >= p.s[si].beg && idx < p.s[si].end) {
            int li = idx - p.s[si].beg;
            int Ncol = p.s[si].Ncol, K0 = p.s[si].K0;
            int kq = li & 7;
            int t = li >> 3;
            int c15 = t & 15; t >>= 4;
            int k8 = t & 3;  t >>= 2;
            int nb = Ncol >> 4;
            int cb = t % nb;
            int ks = t / nb;
            int col = cb * 16 + c15;
            int k = ks * 32 + k8 * 8 + kq;
            float v = (k < K0) ? p.s[si].a[(size_t)k * Ncol + col]
                               : p.s[si].b[(size_t)(k - K0) * Ncol + col];
            p.s[si].dst[li] = f2b(v);
        }
    }
}

// ---------------- CSR build ----------------

__global__ void k_count(const int* __restrict__ dst, int* __restrict__ deg) {
    int e = blockIdx.x * blockDim.x + threadIdx.x;
    if (e < N_EDGES) atomicAdd(&deg[dst[e]], 1);
}

__global__ void k_scan1(const int* __restrict__ deg, int* __restrict__ excl,
                        int* __restrict__ bsum, int n) {
    __shared__ int sh[512];
    int t = threadIdx.x;
    int base = blockIdx.x * 2048 + t * 4;
    int v0 = (base + 0 < n) ? deg[base + 0] : 0;
    int v1 = (base + 1 < n) ? deg[base + 1] : 0;
    int v2 = (base + 2 < n) ? deg[base + 2] : 0;
    int v3 = (base + 3 < n) ? deg[base + 3] : 0;
    int tot = v0 + v1 + v2 + v3;
    sh[t] = tot;
    __syncthreads();
    for (int off = 1; off < 512; off <<= 1) {
        int x = (t >= off) ? sh[t - off] : 0;
        __syncthreads();
        sh[t] += x;
        __syncthreads();
    }
    int run = sh[t] - tot;
    if (base + 0 < n) excl[base + 0] = run; run += v0;
    if (base + 1 < n) excl[base + 1] = run; run += v1;
    if (base + 2 < n) excl[base + 2] = run; run += v2;
    if (base + 3 < n) excl[base + 3] = run;
    if (t == 511) bsum[blockIdx.x] = sh[t];
}

__global__ void k_scan2(int* __restrict__ bsum, int nb) {
    __shared__ int sh[64];
    int t = threadIdx.x;
    int v = (t < nb) ? bsum[t] : 0;
    sh[t] = v;
    __syncthreads();
    for (int off = 1; off < 64; off <<= 1) {
        int x = (t >= off) ? sh[t - off] : 0;
        __syncthreads();
        sh[t] += x;
        __syncthreads();
    }
    if (t < nb) bsum[t] = sh[t] - v;
}

__global__ void k_scan3(int* __restrict__ excl, const int* __restrict__ bsum,
                        int* __restrict__ cursor, int n) {
    int i = blockIdx.x * blockDim.x + threadIdx.x;
    if (i < n) {
        int v = excl[i] + bsum[i >> 11];
        excl[i] = v;
        cursor[i] = v;
    }
}

__global__ void k_scatter(const int* __restrict__ src, const int* __restrict__ dst,
                          int* __restrict__ cursor, int* __restrict__ esrc) {
    int e = blockIdx.x * blockDim.x + threadIdx.x;
    if (e < N_EDGES) {
        int p = atomicAdd(&cursor[dst[e]], 1);
        esrc[p] = src[e];
    }
}

// ---------------- segment-max aggregation (keyed u16 domain) ----------------

template<int CHUNKS>
__global__ __launch_bounds__(256) void k_agg(
    const u16* __restrict__ keyed,
    const int* __restrict__ indptr, const int* __restrict__ deg,
    const int* __restrict__ iend, const int* __restrict__ esrc,
    u16* __restrict__ agg, u16* __restrict__ aggC) {
    __shared__ int se[512];
    __shared__ int sinfo[2];
    const int b4 = blockIdx.x * 4;
    if (threadIdx.x == 0) {
        sinfo[0] = indptr[b4];
        sinfo[1] = iend[b4 + 3];
    }
    __syncthreads();
    const int sbase = sinfo[0];
    const int slen = sinfo[1] - sbase;
    const bool useLds = slen <= 512;
    if (useLds) {
        for (int i = threadIdx.x; i < slen; i += 256) se[i] = esrc[sbase + i];
    }
    __syncthreads();

    const int node = b4 + (threadIdx.x >> 6);
    const int lane = threadIdx.x & 63;
    constexpr int ACTIVE = (CHUNKS == 32) ? 64 : 48;
    const int e_sub = (CHUNKS == 32) ? (lane >> 5) : (lane >= 24 ? 1 : 0);
    int ch = lane - e_sub * CHUNKS;
    if (ch < 0 || ch >= CHUNKS) ch = 0;
    const int start = indptr[node];
    const int d = deg[node];
    const u16* bp = keyed + ((CHUNKS == 32) ? 0 : 64) + ch * 8;

    u32x4 m = {0u, 0u, 0u, 0u};

    if (lane < ACTIVE && d > 0) {
        const int rounds = (d + 7) >> 3;
        const int lbase = start - sbase;
        for (int rr = 0; rr < rounds; ++rr) {
            const int b0 = rr * 8 + e_sub;
            const int dm1 = d - 1;
            int i0 = min(b0, dm1), i1 = min(b0 + 2, dm1);
            int i2 = min(b0 + 4, dm1), i3 = min(b0 + 6, dm1);
            int s0, s1, s2, s3;
            if (useLds) {
                s0 = se[lbase + i0]; s1 = se[lbase + i1];
                s2 = se[lbase + i2]; s3 = se[lbase + i3];
            } else {
                s0 = esrc[start + i0]; s1 = esrc[start + i1];
                s2 = esrc[start + i2]; s3 = esrc[start + i3];
            }
            u32x4 v0 = *(const u32x4*)(bp + (size_t)s0 * 256);
            u32x4 v1 = *(const u32x4*)(bp + (size_t)s1 * 256);
            u32x4 v2 = *(const u32x4*)(bp + (size_t)s2 * 256);
            u32x4 v3 = *(const u32x4*)(bp + (size_t)s3 * 256);
            m = pkmax4(m, pkmax4(pkmax4(v0, v1), pkmax4(v2, v3)));
        }
    }

    if (CHUNKS == 32) {
        m.x = pkmax(m.x, __shfl_xor(m.x, 32, 64));
        m.y = pkmax(m.y, __shfl_xor(m.y, 32, 64));
        m.z = pkmax(m.z, __shfl_xor(m.z, 32, 64));
        m.w = pkmax(m.w, __shfl_xor(m.w, 32, 64));
    } else {
        m.x = pkmax(m.x, __shfl(m.x, lane + 24, 64));
        m.y = pkmax(m.y, __shfl(m.y, lane + 24, 64));
        m.z = pkmax(m.z, __shfl(m.z, lane + 24, 64));
        m.w = pkmax(m.w, __shfl(m.w, lane + 24, 64));
    }

    unsigned wv[4] = {m.x, m.y, m.z, m.w};
    ushort8 o;
    #pragma unroll
    for (int j = 0; j < 4; ++j) {
        u16 klo = (u16)(wv[j] & 0xFFFFu), khi = (u16)(wv[j] >> 16);
        o[2 * j]     = (d > 0) ? unkey(klo) : (u16)0;
        o[2 * j + 1] = (d > 0) ? unkey(khi) : (u16)0;
    }

    if (CHUNKS == 32) {
        if (lane < 32) {
            *(ushort8*)(agg + (size_t)node * 256 + lane * 8) = o;
            if (lane < 8)
                *(ushort8*)(aggC + (size_t)node * 64 + lane * 8) = o;
        }
    } else {
        if (lane < 24) {
            *(ushort8*)(agg + (size_t)node * 256 + 64 + lane * 8) = o;
        } else if (lane >= 48 && lane < 56) {
            const int c2 = lane - 48;
            ushort8 v = *(const ushort8*)(aggC + (size_t)node * 64 + c2 * 8);
            *(ushort8*)(agg + (size_t)node * 256 + c2 * 8) = v;
        }
    }
}

// ---------------- MFMA GEMM (sage): s = concat(agg|conf|x) @ Bt^T + bias ----
// Hoisted incremental staging; fragment-order LDS (conflict-free ds_read).
// Epilogue: fragments -> row-major padded LDS image -> coalesced 16B stores.

template<int BN>
__global__ __launch_bounds__(512) void k_gemm(
    const u16* __restrict__ A0, int K0,
    const u16* __restrict__ A1, int K1,
    const u16* __restrict__ A2, int K2,
    const u16* __restrict__ Bt,
    const float* __restrict__ bias,
    u16* __restrict__ outb,
    int nrows)
{
    constexpr int FN = BN / 64;
    constexpr int ASZ = 128 * 32;
    __shared__ u16 lds[2][ASZ + BN * 32] __attribute__((aligned(16)));

    const int tid = threadIdx.x;
    const int wave = tid >> 6;
    const int lane = tid & 63;
    const int wr = wave >> 2;
    const int wc = wave & 3;
    const int rowbase = blockIdx.x * 128;
    const int nk = (K0 + K1 + K2) >> 5;

    const int arow = ((tid >> 6) << 4) | (tid & 15);
    int grow = rowbase + arow; if (grow >= nrows) grow = nrows - 1;
    const int ak8 = (tid >> 4) & 3;
    const u16* segp[3] = {A0, A1, A2};
    const int segK[3] = {K0, K1, K2};
    int seg = 0;
    const u16* gA = segp[0] + (size_t)grow * segK[0] + ak8 * 8;
    int segleft = segK[0] >> 5;
    const u16* gB0 = Bt + (size_t)tid * 8;
    const u16* gB1 = Bt + (size_t)(512 + tid) * 8;
    const int wb = wave * 512;

    auto adv = [&]() {
        gA += 32;
        if (--segleft == 0) {
            while (seg < 2) {
                ++seg;
                if (segK[seg] > 0) {
                    gA = segp[seg] + (size_t)grow * segK[seg] + ak8 * 8;
                    segleft = segK[seg] >> 5;
                    break;
                }
            }
        }
        gB0 += BN * 32;
        gB1 += BN * 32;
    };
    auto stage = [&](int buf) {
        gload_lds16(gA, &lds[buf][wb]);
        gload_lds16(gB0, &lds[buf][ASZ + wb]);
        if constexpr (BN == 256) {
            gload_lds16(gB1, &lds[buf][ASZ + 4096 + wb]);
        } else {
            if (tid < 256) gload_lds16(gB1, &lds[buf][ASZ + 4096 + wb]);
        }
    };

    f32x4 zero = {0.f, 0.f, 0.f, 0.f};
    f32x4 acc[4][FN];
    #pragma unroll
    for (int fm = 0; fm < 4; ++fm)
        #pragma unroll
        for (int fn = 0; fn < FN; ++fn)
            acc[fm][fn] = zero;

    stage(0); adv();
    __syncthreads();

    const int l15 = lane & 15, l4 = lane >> 4;

    for (int ks = 0; ks < nk; ++ks) {
        const int cur = ks & 1;
        if (ks + 1 < nk) { stage(cur ^ 1); adv(); }
        const u16* la = &lds[cur][0];
        const u16* lb = &lds[cur][ASZ];
        bf16x8 a[4], b[FN];
        #pragma unroll
        for (int fm = 0; fm < 4; ++fm)
            a[fm] = *(const bf16x8*)(la + (wr * 4 + fm) * 512 + lane * 8);
        #pragma unroll
        for (int fn = 0; fn < FN; ++fn)
            b[fn] = *(const bf16x8*)(lb + (wc * FN + fn) * 512 + lane * 8);
        #pragma unroll
        for (int fm = 0; fm < 4; ++fm)
            #pragma unroll
            for (int fn = 0; fn < FN; ++fn)
                acc[fm][fn] = __builtin_amdgcn_mfma_f32_16x16x32_bf16(a[fm], b[fn], acc[fm][fn], 0, 0, 0);
        __syncthreads();
    }

    // epilogue: two 128-col chunks through the LDS image, vector stores
    u16* sbuf = &lds[0][0];   // image max 127*136+127 = 17399 < 24576 u16
    #pragma unroll
    for (int chunk = 0; chunk < 2; ++chunk) {
        if ((wc >> 1) == chunk) {
            const int cbase = (wc & 1) * 64;
            #pragma unroll
            for (int fn = 0; fn < FN; ++fn) {
                const int cp = cbase + fn * 16 + l15;
                const float bs = bias[chunk * 128 + cp];
                #pragma unroll
                for (int fm = 0; fm < 4; ++fm) {
                    const int rbase = wr * 64 + fm * 16 + l4 * 4;
                    #pragma unroll
                    for (int r = 0; r < 4; ++r)
                        sbuf[simgG(rbase + r, cp)] = f2b(acc[fm][fn][r] + bs);
                }
            }
        }
        __syncthreads();
        #pragma unroll
        for (int j = 0; j < 4; ++j) {
            const int chk = j * 512 + tid;        // 2048 chunks = 128r x 16c
            const int row = chk >> 4;
            const int cp = (chk & 15) * 8;
            const int gr = rowbase + row;
            if (gr < nrows) {
                ushort8 hv = *(const ushort8*)&sbuf[simgG(row, cp)];
                *(ushort8*)(outb + (size_t)gr * 256 + chunk * 128 + cp) = hv;
            }
        }
        __syncthreads();
    }
}

// ---------------- fused double-GEMM ----------------
// Phase 1: h = lrelu(concat(A0|A1) @ B1t^T + bias1)  (h kept in LDS, frag order)
// Phase 2: y = epilogue( h @ B2t^T + bias2 )         (B2 frags in registers)
// Epilogue staged through row-major padded LDS image -> coalesced vector IO.
// EPI: 4 = lrelu, +resid -> f32 outf    (mlp1 final)
//      5 = lrelu -> bf16 outb + keyed   (prenet final)
//      6 = lrelu, +resid -> bf16 outb + keyed (mlp0 final)

template<int EPI>
__global__ __launch_bounds__(512) void k_fused(
    const u16* __restrict__ A0, int K0,
    const u16* __restrict__ A1, int K1,
    const u16* __restrict__ B1t, const float* __restrict__ bias1,
    const u16* __restrict__ B2t, const float* __restrict__ bias2,
    float* __restrict__ outf, u16* __restrict__ outb,
    const u16* __restrict__ resid16, u16* __restrict__ keyed,
    int nrows)
{
    // u16 units: A dbuf [0,8192); B1 dbuf [8192,20480); h [0,24576);
    // epilogue image [0, 127*200+191 = 25591]. 51184 B static.
    __shared__ u16 lds[25592] __attribute__((aligned(16)));

    const int tid = threadIdx.x;
    const int wave = tid >> 6;
    const int lane = tid & 63;
    const int wr = wave >> 2;
    const int wc = wave & 3;
    const int l15 = lane & 15, l4 = lane >> 4;
    const int rowbase = blockIdx.x * 128;
    const int nk1 = (K0 + K1) >> 5;

    const int arow = ((tid >> 6) << 4) | (tid & 15);
    int grow = rowbase + arow; if (grow >= nrows) grow = nrows - 1;
    const int ak8 = (tid >> 4) & 3;
    const u16* gA = A0 + (size_t)grow * K0 + ak8 * 8;
    int segleft = K0 >> 5;
    const u16* gB0 = B1t + (size_t)tid * 8;
    const u16* gB1 = B1t + (size_t)(512 + tid) * 8;
    const int wb = wave * 512;

    auto adv = [&]() {
        gA += 32;
        if (--segleft == 0 && K1 > 0) {
            gA = A1 + (size_t)grow * K1 + ak8 * 8;
            segleft = K1 >> 5;
        }
        gB0 += 6144;
        gB1 += 6144;
    };
    auto stage = [&](int buf) {
        gload_lds16(gA, &lds[buf * 4096 + wb]);
        gload_lds16(gB0, &lds[8192 + buf * 6144 + wb]);
        if (tid < 256) gload_lds16(gB1, &lds[8192 + buf * 6144 + 4096 + wb]);
    };

    f32x4 zero = {0.f, 0.f, 0.f, 0.f};
    f32x4 acc[4][3];
    #pragma unroll
    for (int fm = 0; fm < 4; ++fm)
        #pragma unroll
        for (int fn = 0; fn < 3; ++fn)
            acc[fm][fn] = zero;

    stage(0); adv();
    __syncthreads();

    for (int ks = 0; ks < nk1; ++ks) {
        const int cur = ks & 1;
        if (ks + 1 < nk1) { stage(cur ^ 1); adv(); }
        const u16* la = &lds[cur * 4096];
        const u16* lb = &lds[8192 + cur * 6144];
        bf16x8 a[4], b[3];
        #pragma unroll
        for (int fm = 0; fm < 4; ++fm)
            a[fm] = *(const bf16x8*)(la + (wr * 4 + fm) * 512 + lane * 8);
        #pragma unroll
        for (int fn = 0; fn < 3; ++fn)
            b[fn] = *(const bf16x8*)(lb + (wc * 3 + fn) * 512 + lane * 8);
        #pragma unroll
        for (int fm = 0; fm < 4; ++fm)
            #pragma unroll
            for (int fn = 0; fn < 3; ++fn)
                acc[fm][fn] = __builtin_amdgcn_mfma_f32_16x16x32_bf16(a[fm], b[fn], acc[fm][fn], 0, 0, 0);
        __syncthreads();
    }

    // phase-1 epilogue: lrelu(acc + bias1) -> h in LDS, A-fragment order
    // (un-padded 128-stride layout: 3*128+127 = 511 < 512, bijective)
    {
        const int c0 = wc * 48;
        #pragma unroll
        for (int fn = 0; fn < 3; ++fn) {
            const int c = c0 + fn * 16 + l15;
            const float bs = bias1[c];
            const int coff = (c >> 5) * 4096 + ((c >> 3) & 3) * 128 + (c & 7);
            #pragma unroll
            for (int fm = 0; fm < 4; ++fm) {
                const int rb = wr * 4 + fm;
                #pragma unroll
                for (int rr = 0; rr < 4; ++rr) {
                    const int r16 = l4 * 4 + rr;
                    float v = acc[fm][fn][rr] + bs;
                    v = (v >= 0.f) ? v : 0.2f * v;
                    lds[coff + rb * 512 + r16 * 8] = f2b(v);
                }
            }
        }
    }
    __syncthreads();

    // phase 2: B2 fragments (L2-hot), pure ds_read + MFMA
    bf16x8 breg[18];
    #pragma unroll
    for (int ks = 0; ks < 6; ++ks)
        #pragma unroll
        for (int fn = 0; fn < 3; ++fn)
            breg[ks * 3 + fn] = *(const bf16x8*)(B2t + (size_t)(ks * 12 + wc * 3 + fn) * 512 + lane * 8);

    f32x4 acc2[4][3];
    #pragma unroll
    for (int fm = 0; fm < 4; ++fm)
        #pragma unroll
        for (int fn = 0; fn < 3; ++fn)
            acc2[fm][fn] = zero;

    #pragma unroll
    for (int ks = 0; ks < 6; ++ks) {
        bf16x8 a2[4];
        #pragma unroll
        for (int fm = 0; fm < 4; ++fm)
            a2[fm] = *(const bf16x8*)(&lds[ks * 4096 + (wr * 4 + fm) * 512 + lane * 8]);
        #pragma unroll
        for (int fm = 0; fm < 4; ++fm)
            #pragma unroll
            for (int fn = 0; fn < 3; ++fn)
                acc2[fm][fn] = __builtin_amdgcn_mfma_f32_16x16x32_bf16(a2[fm], breg[ks * 3 + fn], acc2[fm][fn], 0, 0, 0);
    }
    __syncthreads();   // h dead; reuse LDS for epilogue image

    // stage lrelu(acc2 + bias2) as bf16 into row-major padded image
    {
        const int c0 = wc * 48;
        #pragma unroll
        for (int fn = 0; fn < 3; ++fn) {
            const int c = c0 + fn * 16 + l15;
            const float bs = bias2[c];
            #pragma unroll
            for (int fm = 0; fm < 4; ++fm) {
                const int rbase = wr * 64 + fm * 16 + l4 * 4;
                #pragma unroll
                for (int r = 0; r < 4; ++r) {
                    float v = acc2[fm][fn][r] + bs;
                    v = (v >= 0.f) ? v : 0.2f * v;
                    lds[simgF(rbase + r, c)] = f2b(v);
                }
            }
        }
    }
    __syncthreads();

    // coalesced pass: 3072 chunks (128 rows x 24 x 8 cols), 6 per thread
    #pragma unroll
    for (int j = 0; j < 6; ++j) {
        const int chk = j * 512 + tid;
        const int row = chk / 24;
        const int c = (chk - row * 24) * 8;
        const int gr = rowbase + row;
        if (gr < nrows) {
            ushort8 hv = *(const ushort8*)&lds[simgF(row, c)];
            if (EPI == 4) {
                ushort8 rv = *(const ushort8*)(resid16 + (size_t)gr * 192 + c);
                f32x4 o0, o1;
                #pragma unroll
                for (int k = 0; k < 4; ++k) {
                    o0[k] = b2f(hv[k]) + b2f(rv[k]);
                    o1[k] = b2f(hv[k + 4]) + b2f(rv[k + 4]);
                }
                *(f32x4*)(outf + (size_t)gr * 192 + c) = o0;
                *(f32x4*)(outf + (size_t)gr * 192 + c + 4) = o1;
            } else if (EPI == 5) {
                *(ushort8*)(outb + (size_t)gr * 192 + c) = hv;
                ushort8 kv;
                #pragma unroll
                for (int k = 0; k < 8; ++k) kv[k] = keyb(hv[k]);
                *(ushort8*)(keyed + (size_t)gr * 256 + 64 + c) = kv;
            } else {  // EPI 6
                ushort8 rv = *(const ushort8*)(resid16 + (size_t)gr * 192 + c);
                ushort8 nb, kv;
                #pragma unroll
                for (int k = 0; k < 8; ++k) {
                    u16 hb = f2b(b2f(hv[k]) + b2f(rv[k]));
                    nb[k] = hb;
                    kv[k] = keyb(hb);
                }
                *(ushort8*)(outb + (size_t)gr * 192 + c) = nb;
                *(ushort8*)(keyed + (size_t)gr * 256 + 64 + c) = kv;
            }
        }
    }
}

// ---------------- host ----------------

extern "C" void kernel_launch(void* const* d_in, const int* in_sizes, int n_in,
                              void* d_out, int out_size, void* d_ws, size_t ws_size,
                              hipStream_t stream)
{
    (void)in_sizes; (void)n_in; (void)out_size; (void)ws_size;
    const float* node = (const float*)d_in[0];
    const float* conf = (const float*)d_in[1];
    const int* edges  = (const int*)d_in[2];
    const float* pw0  = (const float*)d_in[3];
    const float* pb0  = (const float*)d_in[4];
    const float* pw1  = (const float*)d_in[5];
    const float* pb1  = (const float*)d_in[6];
    const float* W[14];
    for (int i = 0; i < 14; ++i) W[i] = (const float*)d_in[7 + i];
    float* out = (float*)d_out;
    const int* e_src = edges;
    const int* e_dst = edges + N_EDGES;

    // keyed gather mirror [N,256] u16 aliased onto d_out (see round 3 note)
    u16* keyed = (u16*)d_out;

    char* w = (char*)d_ws;
    auto alloc = [&](size_t b) { char* p = w; w += (b + 255) & ~(size_t)255; return p; };
    u16* conf16 = (u16*)alloc((size_t)N_NODES * 64 * 2);
    u16* node16 = (u16*)alloc((size_t)N_NODES * 192 * 2);
    u16* x16    = (u16*)alloc((size_t)N_NODES * 192 * 2);
    u16* agg16  = (u16*)alloc((size_t)N_NODES * 256 * 2);   // agg, then s (in-place)
    u16* aggC   = (u16*)alloc((size_t)N_NODES * 64 * 2);
    int* deg    = (int*)alloc((size_t)N_NODES * 4);
    int* indptr = (int*)alloc((size_t)N_NODES * 4);
    int* cursor = (int*)alloc((size_t)N_NODES * 4);
    int* esrc   = (int*)alloc((size_t)N_EDGES * 4);
    int* bsum   = (int*)alloc(4096);
    u16* pw0t   = (u16*)alloc((size_t)192 * 256 * 2);
    u16* pw1t   = (u16*)alloc((size_t)192 * 192 * 2);
    u16 *sB[2], *mw0t[2], *mw1t[2];
    for (int l = 0; l < 2; ++l) {
        sB[l]   = (u16*)alloc((size_t)256 * 512 * 2);
        mw0t[l] = (u16*)alloc((size_t)192 * 256 * 2);
        mw1t[l] = (u16*)alloc((size_t)192 * 192 * 2);
    }

    {
        const int tot = N_NODES * 64 / 4 + N_NODES * 192 / 4 + N_NODES / 4;
        k_prep<<<(tot + 255) / 256, 256, 0, stream>>>(conf, node, conf16, node16, keyed, deg);
    }
    {
        PackArgs pa;
        int off = 0;
        auto seg = [&](int i, const float* a, int K0, const float* b, int K1, int Ncol, u16* dst) {
            int sz = Ncol * (K0 + K1);
            pa.s[i] = {a, b, dst, K0, K1, Ncol, off, off + sz};
            off += sz;
        };
        seg(0, pw0, 256, nullptr, 0, 192, pw0t);
        seg(1, pw1, 192, nullptr, 0, 192, pw1t);
        seg(2, W[0], 256, W[2], 256, 256, sB[0]);
        seg(3, W[3], 256, nullptr, 0, 192, mw0t[0]);
        seg(4, W[5], 192, nullptr, 0, 192, mw1t[0]);
        seg(5, W[7], 256, W[9], 256, 256, sB[1]);
        seg(6, W[10], 256, nullptr, 0, 192, mw0t[1]);
        seg(7, W[12], 192, nullptr, 0, 192, mw1t[1]);
        k_pack<<<(off + 255) / 256, 256, 0, stream>>>(pa, off);
    }
    k_count<<<(N_EDGES + 255) / 256, 256, 0, stream>>>(e_dst, deg);
    int nb = (N_NODES + 2047) / 2048;
    k_scan1<<<nb, 512, 0, stream>>>(deg, indptr, bsum, N_NODES);
    k_scan2<<<1, 64, 0, stream>>>(bsum, nb);
    k_scan3<<<(N_NODES + 255) / 256, 256, 0, stream>>>(indptr, bsum, cursor, N_NODES);
    k_scatter<<<(N_EDGES + 255) / 256, 256, 0, stream>>>(e_src, e_dst, cursor, esrc);

    const int gblk = (N_NODES + 127) / 128;   // 782
    // prenet fused: x = lrelu(lrelu([conf|node]@w0+b0)@w1+b1) -> x16 + keyed
    k_fused<5><<<gblk, 512, 0, stream>>>(conf16, 64, node16, 192,
                                         pw0t, pb0, pw1t, pb1,
                                         nullptr, x16, nullptr, keyed, N_NODES);
    for (int l = 0; l < 2; ++l) {
        if (l == 0)
            k_agg<32><<<N_NODES / 4, 256, 0, stream>>>(keyed, indptr, deg, cursor, esrc, agg16, aggC);
        else
            k_agg<24><<<N_NODES / 4, 256, 0, stream>>>(keyed, indptr, deg, cursor, esrc, agg16, aggC);
        // s = agg@wl + bl + [conf|x]@wr   (K=512 fused concat; in-place agg16)
        k_gemm<256><<<gblk, 512, 0, stream>>>(agg16, 256, conf16, 64, x16, 192,
                                              sB[l], W[7*l+1], agg16, N_NODES);
        // fused mlp: x = x + lrelu(lrelu(s@mw0+mb0)@mw1+mb1)
        if (l == 0)
            k_fused<6><<<gblk, 512, 0, stream>>>(agg16, 256, nullptr, 0,
                                                 mw0t[0], W[4], mw1t[0], W[6],
                                                 nullptr, x16, x16, keyed, N_NODES);
        else
            k_fused<4><<<gblk, 512, 0, stream>>>(agg16, 256, nullptr, 0,
                                                 mw0t[1], W[11], mw1t[1], W[13],
                                                 out, nullptr, x16, nullptr, N_NODES);
    }
}